// Round 6
// baseline (385.155 us; speedup 1.0000x reference)
//
#include <hip/hip_runtime.h>
#include <stdint.h>
#include <stddef.h>

// ============================================================================
// R6 = INSTRUMENTATION ROUND: identical to R5 except resample_kernel is
// launched TWICE (idempotent). dur_us(R6) - dur_us(R5) = resample duration.
// This resolves the fused-vs-resample attribution that R3/R4/R5 guesses
// failed to localize.
// ============================================================================

// Problem constants (match reference setup_inputs)
#define B_    16
#define P_    16
#define S_    512
#define D_    256
#define DFF_  1024
#define VOCAB_ 5000
#define T_    256
#define ROWS_ 256        // B*P
#define EPS_  1e-6f

#define PARTITIONABLE 1  // jax_threefry_partitionable=True (verified in R1)

// ---------------- threefry2x32 (JAX reference cipher) ----------------
__host__ __device__ __forceinline__ uint32_t rotl32_(uint32_t x, int d) {
  return (x << d) | (x >> (32 - d));
}

__host__ __device__ __forceinline__ void threefry2x32_(uint32_t k0, uint32_t k1,
                                                       uint32_t x0, uint32_t x1,
                                                       uint32_t& o0, uint32_t& o1) {
  uint32_t ks2 = k0 ^ k1 ^ 0x1BD11BDAu;
  x0 += k0; x1 += k1;
  x0 += x1; x1 = rotl32_(x1, 13); x1 ^= x0;
  x0 += x1; x1 = rotl32_(x1, 15); x1 ^= x0;
  x0 += x1; x1 = rotl32_(x1, 26); x1 ^= x0;
  x0 += x1; x1 = rotl32_(x1,  6); x1 ^= x0;
  x0 += k1; x1 += ks2 + 1u;
  x0 += x1; x1 = rotl32_(x1, 17); x1 ^= x0;
  x0 += x1; x1 = rotl32_(x1, 29); x1 ^= x0;
  x0 += x1; x1 = rotl32_(x1, 16); x1 ^= x0;
  x0 += x1; x1 = rotl32_(x1, 24); x1 ^= x0;
  x0 += ks2; x1 += k0 + 2u;
  x0 += x1; x1 = rotl32_(x1, 13); x1 ^= x0;
  x0 += x1; x1 = rotl32_(x1, 15); x1 ^= x0;
  x0 += x1; x1 = rotl32_(x1, 26); x1 ^= x0;
  x0 += x1; x1 = rotl32_(x1,  6); x1 ^= x0;
  x0 += k0; x1 += k1 + 3u;
  x0 += x1; x1 = rotl32_(x1, 17); x1 ^= x0;
  x0 += x1; x1 = rotl32_(x1, 29); x1 ^= x0;
  x0 += x1; x1 = rotl32_(x1, 16); x1 ^= x0;
  x0 += x1; x1 = rotl32_(x1, 24); x1 ^= x0;
  x0 += k1; x1 += ks2 + 4u;
  x0 += x1; x1 = rotl32_(x1, 13); x1 ^= x0;
  x0 += x1; x1 = rotl32_(x1, 15); x1 ^= x0;
  x0 += x1; x1 = rotl32_(x1, 26); x1 ^= x0;
  x0 += x1; x1 = rotl32_(x1,  6); x1 ^= x0;
  x0 += ks2; x1 += k0 + 5u;
  o0 = x0; o1 = x1;
}

__device__ __forceinline__ uint32_t jax_bits(uint32_t k0, uint32_t k1,
                                             uint32_t i) {
#if PARTITIONABLE
  uint32_t o0, o1;
  threefry2x32_(k0, k1, 0u, i, o0, o1);
  return o0 ^ o1;
#else
  return 0u;  // legacy path unused (verified partitionable in R1)
#endif
}

__device__ __forceinline__ float bits_to_u01(uint32_t b) {
  return __uint_as_float((b >> 9) | 0x3F800000u) - 1.0f;
}

// XLA f32 ErfInv (Giles polynomial)
__device__ __forceinline__ float erfinv32(float x) {
  float w = -log1pf(-x * x);
  float p;
  if (w < 5.0f) {
    w -= 2.5f;
    p = 2.81022636e-08f;
    p = fmaf(p, w, 3.43273939e-07f);
    p = fmaf(p, w, -3.5233877e-06f);
    p = fmaf(p, w, -4.39150654e-06f);
    p = fmaf(p, w, 0.00021858087f);
    p = fmaf(p, w, -0.00125372503f);
    p = fmaf(p, w, -0.00417768164f);
    p = fmaf(p, w, 0.246640727f);
    p = fmaf(p, w, 1.50140941f);
  } else {
    w = sqrtf(w) - 3.0f;
    p = -0.000200214257f;
    p = fmaf(p, w, 0.000100950558f);
    p = fmaf(p, w, 0.00134934322f);
    p = fmaf(p, w, -0.00367342844f);
    p = fmaf(p, w, 0.00573950773f);
    p = fmaf(p, w, -0.0076224613f);
    p = fmaf(p, w, 0.00943887047f);
    p = fmaf(p, w, 1.00167406f);
    p = fmaf(p, w, 2.83297682f);
  }
  return p * x;
}

__device__ __forceinline__ float jax_normal(uint32_t k0, uint32_t k1,
                                            uint32_t i) {
  float u01 = bits_to_u01(jax_bits(k0, k1, i));
  const float lo = -0.99999994f;
  float u = __fadd_rn(__fmul_rn(u01, 2.0f), lo);
  u = fmaxf(lo, u);
  return 1.41421356f * erfinv32(u);
}

__device__ __forceinline__ float jax_gumbel(uint32_t k0, uint32_t k1,
                                            uint32_t i) {
  float u01 = bits_to_u01(jax_bits(k0, k1, i));
  const float tiny = 1.17549435e-38f;
  float u = __fadd_rn(__fmul_rn(u01, 1.0f), tiny);
  u = fmaxf(tiny, u);
  return -logf(-logf(u));
}

// ---------------- 1024-thread block reductions (wave shfl + 16-slot LDS) ----
__device__ __forceinline__ float blk_sum(float v, float* red, int tid) {
  #pragma unroll
  for (int off = 32; off > 0; off >>= 1) v += __shfl_xor(v, off, 64);
  if ((tid & 63) == 0) red[tid >> 6] = v;
  __syncthreads();
  if (tid == 0) {
    float s = 0.f;
    #pragma unroll
    for (int i = 0; i < 16; i++) s += red[i];
    red[16] = s;
  }
  __syncthreads();
  float r = red[16];
  __syncthreads();
  return r;
}
__device__ __forceinline__ float blk_max(float v, float* red, int tid) {
  #pragma unroll
  for (int off = 32; off > 0; off >>= 1) v = fmaxf(v, __shfl_xor(v, off, 64));
  if ((tid & 63) == 0) red[tid >> 6] = v;
  __syncthreads();
  if (tid == 0) {
    float s = -INFINITY;
    #pragma unroll
    for (int i = 0; i < 16; i++) s = fmaxf(s, red[i]);
    red[16] = s;
  }
  __syncthreads();
  float r = red[16];
  __syncthreads();
  return r;
}

// ---------------- fused per-row kernel (float4 dot phases) ------------------
__global__ __launch_bounds__(1024) void fused_row_kernel(
    const float* __restrict__ x,
    const float* __restrict__ Kin, const float* __restrict__ Vin,
    const float* __restrict__ wq, const float* __restrict__ bq,
    const float* __restrict__ wk, const float* __restrict__ bk,
    const float* __restrict__ wv, const float* __restrict__ bv,
    const float* __restrict__ wo, const float* __restrict__ bo,
    const float* __restrict__ w1, const float* __restrict__ b1,
    const float* __restrict__ w2, const float* __restrict__ b2,
    const float* __restrict__ ln1g, const float* __restrict__ ln1b,
    const float* __restrict__ ln2g, const float* __restrict__ ln2b,
    const float* __restrict__ sigmas,
    float* __restrict__ kws, float* __restrict__ vws,
    float* __restrict__ attn_out, float* __restrict__ noiseq_out,
    float* __restrict__ noisez_out, float* __restrict__ r_out,
    uint32_t kq0, uint32_t kq1, uint32_t kk0, uint32_t kk1,
    uint32_t kv0, uint32_t kv1, uint32_t kz0, uint32_t kz1) {
  __shared__ float xs[D_], qs[D_], ksh[D_], vsh[D_], z0s[D_], os[D_];
  __shared__ float att[T_ + 4];
  __shared__ float hs[DFF_];
  __shared__ float4 scq[16][64];   // 16KB  (also reused as [4][256] for FFN1)
  __shared__ float4 sck[16][64];   // 16KB
  __shared__ float4 scv[16][64];   // 16KB
  __shared__ float red[32];
  const int row = blockIdx.x, t = threadIdx.x;
  const int cg = t & 63;           // float4 col group (64 groups x 4 cols)
  const int sl = t >> 6;           // 0..15 K-slice

  if (t < D_) xs[t] = x[row * D_ + t];
  __syncthreads();

  // ---- QKV partials: slice sl covers e in [sl*16, sl*16+16), float4 cols --
  {
    const float4* wqf = (const float4*)wq;
    const float4* wkf = (const float4*)wk;
    const float4* wvf = (const float4*)wv;
    float4 aq = {0,0,0,0}, ak = {0,0,0,0}, av = {0,0,0,0};
    const int e0 = sl * 16;
    #pragma unroll
    for (int e = e0; e < e0 + 16; e++) {
      float xe = xs[e];
      float4 a = wqf[e * 64 + cg];
      float4 b = wkf[e * 64 + cg];
      float4 c = wvf[e * 64 + cg];
      aq.x = fmaf(xe, a.x, aq.x); aq.y = fmaf(xe, a.y, aq.y);
      aq.z = fmaf(xe, a.z, aq.z); aq.w = fmaf(xe, a.w, aq.w);
      ak.x = fmaf(xe, b.x, ak.x); ak.y = fmaf(xe, b.y, ak.y);
      ak.z = fmaf(xe, b.z, ak.z); ak.w = fmaf(xe, b.w, ak.w);
      av.x = fmaf(xe, c.x, av.x); av.y = fmaf(xe, c.y, av.y);
      av.z = fmaf(xe, c.z, av.z); av.w = fmaf(xe, c.w, av.w);
    }
    scq[sl][cg] = aq; sck[sl][cg] = ak; scv[sl][cg] = av;
  }
  __syncthreads();
  // ---- reduce + bias + noise: 3 groups of 256 threads (q,k,v parallel) ----
  if (t < 768) {
    const int m = t >> 8, c = t & 255;
    const float* sc = (m == 0) ? (const float*)scq
                    : (m == 1) ? (const float*)sck : (const float*)scv;
    float s = 0.f;
    #pragma unroll
    for (int j = 0; j < 16; j++) s += sc[j * 256 + c];
    float bias = ((m == 0) ? bq : (m == 1) ? bk : bv)[c];
    float base = bias + s;
    uint32_t i = (uint32_t)row * D_ + c;
    uint32_t a0 = (m == 0) ? kq0 : (m == 1) ? kk0 : kv0;
    uint32_t a1 = (m == 0) ? kq1 : (m == 1) ? kk1 : kv1;
    float val = base + sigmas[m] * jax_normal(a0, a1, i);
    if (m == 0)      { qs[c] = val; noiseq_out[i] = val - base; }
    else if (m == 1) { ksh[c] = val; kws[i] = val; }
    else             { vsh[c] = val; vws[i] = val; }
  }
  __syncthreads();

  // ---- logits: 16 waves, 4 s-values per wave per round, float4 dot ----
  {
    const int wid = t >> 6, lane = t & 63;
    float4 myq = ((const float4*)qs)[lane];
    for (int s0 = wid * 4; s0 <= T_; s0 += 64) {
      #pragma unroll
      for (int j = 0; j < 4; j++) {
        int s = s0 + j;
        if (s <= T_) {
          const float* Krow = (s == T_) ? ksh
                                        : (Kin + ((size_t)row * S_ + s) * D_);
          float4 k4 = ((const float4*)Krow)[lane];
          float rr = myq.x * k4.x + myq.y * k4.y + myq.z * k4.z + myq.w * k4.w;
          #pragma unroll
          for (int off = 32; off > 0; off >>= 1) rr += __shfl_xor(rr, off, 64);
          if (lane == 0) att[s] = rr * 0.0625f;   // / sqrt(256)
        }
      }
    }
  }
  __syncthreads();

  // ---- softmax over 257 logits ----
  {
    float v = (t <= T_) ? att[t] : -INFINITY;
    float mx = blk_max(v, red, t);
    float e = (t <= T_) ? expf(att[t] - mx) : 0.f;
    float sum = blk_sum(e, red, t);
    if (t <= T_) {
      float a = e / sum;
      att[t] = a;
      attn_out[(size_t)row * (T_ + 1) + t] = a;
    }
  }
  __syncthreads();

  // ---- z0 = attn @ Vw: slice sl covers s in [sl*16, sl*16+16) ----
  {
    const float4* Vf = (const float4*)(Vin + (size_t)row * S_ * D_);
    float4 acc = {0,0,0,0};
    const int s0 = sl * 16;
    #pragma unroll
    for (int s = s0; s < s0 + 16; s++) {
      float a = att[s];
      float4 v4 = Vf[s * 64 + cg];
      acc.x = fmaf(a, v4.x, acc.x); acc.y = fmaf(a, v4.y, acc.y);
      acc.z = fmaf(a, v4.z, acc.z); acc.w = fmaf(a, v4.w, acc.w);
    }
    scq[sl][cg] = acc;
  }
  __syncthreads();
  if (t < D_) {
    float s = 0.f;
    #pragma unroll
    for (int j = 0; j < 16; j++) s += ((const float*)scq)[j * 256 + t];
    z0s[t] = s + att[T_] * vsh[t];
  }
  __syncthreads();

  // ---- z = z0 @ wo + bo + noise; y = z + x; LN1 ----
  {
    const float4* wof = (const float4*)wo;
    float4 acc = {0,0,0,0};
    const int e0 = sl * 16;
    #pragma unroll
    for (int e = e0; e < e0 + 16; e++) {
      float ze = z0s[e];
      float4 w4 = wof[e * 64 + cg];
      acc.x = fmaf(ze, w4.x, acc.x); acc.y = fmaf(ze, w4.y, acc.y);
      acc.z = fmaf(ze, w4.z, acc.z); acc.w = fmaf(ze, w4.w, acc.w);
    }
    sck[sl][cg] = acc;
  }
  __syncthreads();
  if (t < D_) {
    float s = 0.f;
    #pragma unroll
    for (int j = 0; j < 16; j++) s += ((const float*)sck)[j * 256 + t];
    float zp = bo[t] + s;
    uint32_t i = (uint32_t)row * D_ + t;
    float zn = zp + sigmas[3] * jax_normal(kz0, kz1, i);
    noisez_out[i] = zn - zp;
    z0s[t] = zn + xs[t];     // reuse z0s as y
  }
  __syncthreads();
  {
    float y = (t < D_) ? z0s[t] : 0.f;
    float mu = blk_sum(y, red, t) * (1.0f / 256.0f);
    float dv = (t < D_) ? (z0s[t] - mu) : 0.f;
    float var = blk_sum(dv * dv, red, t) * (1.0f / 256.0f);
    if (t < D_) os[t] = dv * rsqrtf(var + EPS_) * ln1g[t] + ln1b[t];
  }
  __syncthreads();

  // ---- FFN1: 256 col-groups (f4) x 4 e-slices of 64 ----
  {
    const int cg8 = t & 255, es = t >> 8;
    const float4* w1f = (const float4*)w1;   // [256 rows][256 f4 groups]
    float4 acc = {0,0,0,0};
    const int e0 = es * 64;
    #pragma unroll 8
    for (int e = e0; e < e0 + 64; e++) {
      float oe = os[e];
      float4 w4 = w1f[e * 256 + cg8];
      acc.x = fmaf(oe, w4.x, acc.x); acc.y = fmaf(oe, w4.y, acc.y);
      acc.z = fmaf(oe, w4.z, acc.z); acc.w = fmaf(oe, w4.w, acc.w);
    }
    ((float4*)scq)[es * 256 + cg8] = acc;    // scq as [4][256] f4 (16KB)
  }
  __syncthreads();
  {
    float s = 0.f;
    #pragma unroll
    for (int j = 0; j < 4; j++) s += ((const float*)scq)[j * 1024 + t];
    hs[t] = fmaxf(b1[t] + s, 0.f);
  }
  __syncthreads();

  // ---- FFN2: 64 col-groups (f4) x 16 e-slices of 64 ----
  {
    const float4* w2f = (const float4*)w2;   // [1024 rows][64 f4 groups]
    float4 acc = {0,0,0,0};
    const int e0 = sl * 64;
    #pragma unroll 8
    for (int e = e0; e < e0 + 64; e++) {
      float he = hs[e];
      float4 w4 = w2f[e * 64 + cg];
      acc.x = fmaf(he, w4.x, acc.x); acc.y = fmaf(he, w4.y, acc.y);
      acc.z = fmaf(he, w4.z, acc.z); acc.w = fmaf(he, w4.w, acc.w);
    }
    scv[sl][cg] = acc;
  }
  __syncthreads();
  if (t < D_) {
    float s = 0.f;
    #pragma unroll
    for (int j = 0; j < 16; j++) s += ((const float*)scv)[j * 256 + t];
    z0s[t] = b2[t] + s + os[t];
  }
  __syncthreads();
  {
    float y = (t < D_) ? z0s[t] : 0.f;
    float mu = blk_sum(y, red, t) * (1.0f / 256.0f);
    float dv = (t < D_) ? (z0s[t] - mu) : 0.f;
    float var = blk_sum(dv * dv, red, t) * (1.0f / 256.0f);
    if (t < D_)
      r_out[(size_t)row * D_ + t] = dv * rsqrtf(var + EPS_) * ln2g[t] + ln2b[t];
  }
}

// ---------------- preds = r @ w_out (256x5000x256) ----------------
__global__ __launch_bounds__(256) void preds_kernel(
    const float* __restrict__ r, const float* __restrict__ w_out,
    float* __restrict__ preds) {
  int tid = threadIdx.x;
  int col = blockIdx.x * 250 + tid;
  int rb = blockIdx.y * 16;
  if (tid >= 250) return;
  float acc[16];
  #pragma unroll
  for (int m = 0; m < 16; m++) acc[m] = 0.f;
  #pragma unroll 4
  for (int e = 0; e < D_; e++) {
    float wv = w_out[(size_t)e * VOCAB_ + col];
    #pragma unroll
    for (int m = 0; m < 16; m++)
      acc[m] = fmaf(r[(size_t)(rb + m) * D_ + e], wv, acc[m]);
  }
  #pragma unroll
  for (int m = 0; m < 16; m++)
    preds[(size_t)(rb + m) * VOCAB_ + col] = acc[m];
}

// ---------------- softmax-pick w = probas[y] ----------------
__device__ __forceinline__ float red256_sum(float v, float* red, int tid) {
  red[tid] = v; __syncthreads();
  #pragma unroll
  for (int st = 128; st > 0; st >>= 1) {
    if (tid < st) red[tid] += red[tid + st];
    __syncthreads();
  }
  float r = red[0]; __syncthreads();
  return r;
}
__device__ __forceinline__ float red256_max(float v, float* red, int tid) {
  red[tid] = v; __syncthreads();
  #pragma unroll
  for (int st = 128; st > 0; st >>= 1) {
    if (tid < st) red[tid] = fmaxf(red[tid], red[tid + st]);
    __syncthreads();
  }
  float r = red[0]; __syncthreads();
  return r;
}

__global__ __launch_bounds__(256) void pick_kernel(
    const float* __restrict__ preds, const int* __restrict__ y,
    float* __restrict__ w) {
  __shared__ float red[256];
  int row = blockIdx.x, tid = threadIdx.x;
  const float* pr = preds + (size_t)row * VOCAB_;
  float m = -INFINITY;
  for (int j = tid; j < VOCAB_; j += 256) m = fmaxf(m, pr[j]);
  float mx = red256_max(m, red, tid);
  float s = 0.f;
  for (int j = tid; j < VOCAB_; j += 256) s += expf(pr[j] - mx);
  float sum = red256_sum(s, red, tid);
  if (tid == 0) w[row] = expf(pr[y[row]] - mx) / sum;
}

// ---------------- w_norm + gumbel-max categorical -> i_t ----------------
__global__ __launch_bounds__(256) void cat_kernel(
    const float* __restrict__ w, int* __restrict__ i_t,
    uint32_t kc0, uint32_t kc1) {
  __shared__ float wv[256];
  __shared__ float wn[256];
  int tid = threadIdx.x;
  int b = tid >> 4;
  wv[tid] = w[tid];
  __syncthreads();
  float mx = -INFINITY;
  for (int j = 0; j < 16; j++) mx = fmaxf(mx, wv[b * 16 + j]);
  float ev = expf(wv[tid] - mx);
  wn[tid] = ev;
  __syncthreads();
  float sum = 0.f;
  for (int j = 0; j < 16; j++) sum += wn[b * 16 + j];
  __syncthreads();
  wn[tid] = ev / sum;
  __syncthreads();
  float best = -INFINITY;
  int bi = 0;
  for (int j = 0; j < 16; j++) {
    uint32_t idx = (uint32_t)tid * 16u + (uint32_t)j;
    float g = jax_gumbel(kc0, kc1, idx);
    float sc = g + wn[b * 16 + j];
    if (sc > best) { best = sc; bi = j; }
  }
  i_t[tid] = bi;
}

// ---------------- resample/copy K,V,R (R2 flat form — best measured) -------
__global__ __launch_bounds__(256) void resample_kernel(
    const float4* __restrict__ Kin, const float4* __restrict__ Vin,
    const float4* __restrict__ Rin,
    const float4* __restrict__ knew, const float4* __restrict__ vnew,
    const float4* __restrict__ rnew,
    const int* __restrict__ i_t,
    float4* __restrict__ Kout, float4* __restrict__ Vout,
    float4* __restrict__ Rout) {
  uint32_t idx = blockIdx.x * 256u + threadIdx.x;
  uint32_t d4 = idx & 63u;
  uint32_t s  = (idx >> 6) & 511u;
  uint32_t p  = (idx >> 15) & 15u;
  uint32_t b  = idx >> 19;
  const float4* in; const float4* nw; float4* out;
  if (blockIdx.y == 0)      { in = Kin; nw = knew; out = Kout; }
  else if (blockIdx.y == 1) { in = Vin; nw = vnew; out = Vout; }
  else                      { in = Rin; nw = rnew; out = Rout; }
  float4 val;
  if (s > T_) {
    val = in[idx];
  } else {
    uint32_t ip = (uint32_t)i_t[(b << 4) | p];
    if (s == T_) val = nw[(((b << 4) | ip) << 6) | d4];
    else         val = in[(((((b << 4) | ip) << 9) | s) << 6) | d4];
  }
  out[idx] = val;
}

// ---------------- host ----------------
static void compute_subkeys(uint32_t nk[5][2]) {
  const uint32_t k0 = 0u, k1 = 1234u;
  for (uint32_t j = 0; j < 5; j++)
    threefry2x32_(k0, k1, 0u, j, nk[j][0], nk[j][1]);
}

extern "C" void kernel_launch(void* const* d_in, const int* in_sizes, int n_in,
                              void* d_out, int out_size, void* d_ws, size_t ws_size,
                              hipStream_t stream) {
  const float* x    = (const float*)d_in[0];
  const int*   y    = (const int*)d_in[1];
  const float* Kin  = (const float*)d_in[2];
  const float* Vin  = (const float*)d_in[3];
  const float* Rin  = (const float*)d_in[4];
  const float* wq   = (const float*)d_in[5];  const float* bq = (const float*)d_in[6];
  const float* wk   = (const float*)d_in[7];  const float* bk = (const float*)d_in[8];
  const float* wv   = (const float*)d_in[9];  const float* bv = (const float*)d_in[10];
  const float* wo   = (const float*)d_in[11]; const float* bo = (const float*)d_in[12];
  const float* w1   = (const float*)d_in[13]; const float* b1 = (const float*)d_in[14];
  const float* w2   = (const float*)d_in[15]; const float* b2 = (const float*)d_in[16];
  const float* ln1g = (const float*)d_in[17]; const float* ln1b = (const float*)d_in[18];
  const float* ln2g = (const float*)d_in[19]; const float* ln2b = (const float*)d_in[20];
  const float* w_out = (const float*)d_in[21];
  const float* sigmas = (const float*)d_in[22];
  (void)in_sizes; (void)n_in; (void)out_size; (void)ws_size;

  // output layout (flat f32, return order): r, attn, noise_q, noise_z, K, V, R
  float* out        = (float*)d_out;
  float* r_out      = out;
  float* attn_out   = out + 65536;
  float* noiseq_out = out + 131328;
  float* noisez_out = out + 196864;
  float* K_out      = out + 262400;
  float* V_out      = out + 33816832;
  float* R_out      = out + 67371264;

  // workspace layout (floats)
  float* wsf   = (float*)d_ws;
  float* kws   = wsf;                  // 65536
  float* vws   = wsf + 65536;          // 65536
  float* preds = wsf + 131072;         // 1,280,000
  float* wprob = wsf + 1411072;        // 256
  int*   i_t   = (int*)(wsf + 1411328);

  uint32_t nk[5][2];
  compute_subkeys(nk);  // 0=q, 1=k, 2=v, 3=z, 4=categorical

  fused_row_kernel<<<ROWS_, 1024, 0, stream>>>(
      x, Kin, Vin, wq, bq, wk, bk, wv, bv, wo, bo, w1, b1, w2, b2,
      ln1g, ln1b, ln2g, ln2b, sigmas,
      kws, vws, attn_out, noiseq_out, noisez_out, r_out,
      nk[0][0], nk[0][1], nk[1][0], nk[1][1], nk[2][0], nk[2][1],
      nk[3][0], nk[3][1]);
  preds_kernel<<<dim3(20, 16), 256, 0, stream>>>(r_out, w_out, preds);
  pick_kernel<<<ROWS_, 256, 0, stream>>>(preds, y, wprob);
  cat_kernel<<<1, 256, 0, stream>>>(wprob, i_t, nk[4][0], nk[4][1]);
  // Launch 1 (the real one)
  resample_kernel<<<dim3(32768, 3), 256, 0, stream>>>(
      (const float4*)Kin, (const float4*)Vin, (const float4*)Rin,
      (const float4*)kws, (const float4*)vws, (const float4*)r_out,
      i_t, (float4*)K_out, (float4*)V_out, (float4*)R_out);
  // Launch 2 (INSTRUMENTATION: idempotent duplicate; dur delta vs R5 =
  // resample_kernel duration). Remove next round.
  resample_kernel<<<dim3(32768, 3), 256, 0, stream>>>(
      (const float4*)Kin, (const float4*)Vin, (const float4*)Rin,
      (const float4*)kws, (const float4*)vws, (const float4*)r_out,
      i_t, (float4*)K_out, (float4*)V_out, (float4*)R_out);
}

// Round 7
// 378.187 us; speedup vs baseline: 1.0184x; 1.0184x over previous
//
#include <hip/hip_runtime.h>
#include <stdint.h>
#include <stddef.h>

// ============================================================================
// R7 = INSTRUMENTATION ROUND 2: identical to R5 except fused_row_kernel is
// launched 3x (idempotent). F = (dur_us - 266.6)/2.
// Known from R6: resample = 118.5 us (6.8 TB/s = fill rate -> AT roofline).
// ============================================================================

// Problem constants (match reference setup_inputs)
#define B_    16
#define P_    16
#define S_    512
#define D_    256
#define DFF_  1024
#define VOCAB_ 5000
#define T_    256
#define ROWS_ 256        // B*P
#define EPS_  1e-6f

#define PARTITIONABLE 1  // jax_threefry_partitionable=True (verified in R1)

// ---------------- threefry2x32 (JAX reference cipher) ----------------
__host__ __device__ __forceinline__ uint32_t rotl32_(uint32_t x, int d) {
  return (x << d) | (x >> (32 - d));
}

__host__ __device__ __forceinline__ void threefry2x32_(uint32_t k0, uint32_t k1,
                                                       uint32_t x0, uint32_t x1,
                                                       uint32_t& o0, uint32_t& o1) {
  uint32_t ks2 = k0 ^ k1 ^ 0x1BD11BDAu;
  x0 += k0; x1 += k1;
  x0 += x1; x1 = rotl32_(x1, 13); x1 ^= x0;
  x0 += x1; x1 = rotl32_(x1, 15); x1 ^= x0;
  x0 += x1; x1 = rotl32_(x1, 26); x1 ^= x0;
  x0 += x1; x1 = rotl32_(x1,  6); x1 ^= x0;
  x0 += k1; x1 += ks2 + 1u;
  x0 += x1; x1 = rotl32_(x1, 17); x1 ^= x0;
  x0 += x1; x1 = rotl32_(x1, 29); x1 ^= x0;
  x0 += x1; x1 = rotl32_(x1, 16); x1 ^= x0;
  x0 += x1; x1 = rotl32_(x1, 24); x1 ^= x0;
  x0 += ks2; x1 += k0 + 2u;
  x0 += x1; x1 = rotl32_(x1, 13); x1 ^= x0;
  x0 += x1; x1 = rotl32_(x1, 15); x1 ^= x0;
  x0 += x1; x1 = rotl32_(x1, 26); x1 ^= x0;
  x0 += x1; x1 = rotl32_(x1,  6); x1 ^= x0;
  x0 += k0; x1 += k1 + 3u;
  x0 += x1; x1 = rotl32_(x1, 17); x1 ^= x0;
  x0 += x1; x1 = rotl32_(x1, 29); x1 ^= x0;
  x0 += x1; x1 = rotl32_(x1, 16); x1 ^= x0;
  x0 += x1; x1 = rotl32_(x1, 24); x1 ^= x0;
  x0 += k1; x1 += ks2 + 4u;
  x0 += x1; x1 = rotl32_(x1, 13); x1 ^= x0;
  x0 += x1; x1 = rotl32_(x1, 15); x1 ^= x0;
  x0 += x1; x1 = rotl32_(x1, 26); x1 ^= x0;
  x0 += x1; x1 = rotl32_(x1,  6); x1 ^= x0;
  x0 += ks2; x1 += k0 + 5u;
  o0 = x0; o1 = x1;
}

__device__ __forceinline__ uint32_t jax_bits(uint32_t k0, uint32_t k1,
                                             uint32_t i) {
#if PARTITIONABLE
  uint32_t o0, o1;
  threefry2x32_(k0, k1, 0u, i, o0, o1);
  return o0 ^ o1;
#else
  return 0u;  // legacy path unused (verified partitionable in R1)
#endif
}

__device__ __forceinline__ float bits_to_u01(uint32_t b) {
  return __uint_as_float((b >> 9) | 0x3F800000u) - 1.0f;
}

// XLA f32 ErfInv (Giles polynomial)
__device__ __forceinline__ float erfinv32(float x) {
  float w = -log1pf(-x * x);
  float p;
  if (w < 5.0f) {
    w -= 2.5f;
    p = 2.81022636e-08f;
    p = fmaf(p, w, 3.43273939e-07f);
    p = fmaf(p, w, -3.5233877e-06f);
    p = fmaf(p, w, -4.39150654e-06f);
    p = fmaf(p, w, 0.00021858087f);
    p = fmaf(p, w, -0.00125372503f);
    p = fmaf(p, w, -0.00417768164f);
    p = fmaf(p, w, 0.246640727f);
    p = fmaf(p, w, 1.50140941f);
  } else {
    w = sqrtf(w) - 3.0f;
    p = -0.000200214257f;
    p = fmaf(p, w, 0.000100950558f);
    p = fmaf(p, w, 0.00134934322f);
    p = fmaf(p, w, -0.00367342844f);
    p = fmaf(p, w, 0.00573950773f);
    p = fmaf(p, w, -0.0076224613f);
    p = fmaf(p, w, 0.00943887047f);
    p = fmaf(p, w, 1.00167406f);
    p = fmaf(p, w, 2.83297682f);
  }
  return p * x;
}

__device__ __forceinline__ float jax_normal(uint32_t k0, uint32_t k1,
                                            uint32_t i) {
  float u01 = bits_to_u01(jax_bits(k0, k1, i));
  const float lo = -0.99999994f;
  float u = __fadd_rn(__fmul_rn(u01, 2.0f), lo);
  u = fmaxf(lo, u);
  return 1.41421356f * erfinv32(u);
}

__device__ __forceinline__ float jax_gumbel(uint32_t k0, uint32_t k1,
                                            uint32_t i) {
  float u01 = bits_to_u01(jax_bits(k0, k1, i));
  const float tiny = 1.17549435e-38f;
  float u = __fadd_rn(__fmul_rn(u01, 1.0f), tiny);
  u = fmaxf(tiny, u);
  return -logf(-logf(u));
}

// ---------------- 1024-thread block reductions (wave shfl + 16-slot LDS) ----
__device__ __forceinline__ float blk_sum(float v, float* red, int tid) {
  #pragma unroll
  for (int off = 32; off > 0; off >>= 1) v += __shfl_xor(v, off, 64);
  if ((tid & 63) == 0) red[tid >> 6] = v;
  __syncthreads();
  if (tid == 0) {
    float s = 0.f;
    #pragma unroll
    for (int i = 0; i < 16; i++) s += red[i];
    red[16] = s;
  }
  __syncthreads();
  float r = red[16];
  __syncthreads();
  return r;
}
__device__ __forceinline__ float blk_max(float v, float* red, int tid) {
  #pragma unroll
  for (int off = 32; off > 0; off >>= 1) v = fmaxf(v, __shfl_xor(v, off, 64));
  if ((tid & 63) == 0) red[tid >> 6] = v;
  __syncthreads();
  if (tid == 0) {
    float s = -INFINITY;
    #pragma unroll
    for (int i = 0; i < 16; i++) s = fmaxf(s, red[i]);
    red[16] = s;
  }
  __syncthreads();
  float r = red[16];
  __syncthreads();
  return r;
}

// ---------------- fused per-row kernel (float4 dot phases) ------------------
__global__ __launch_bounds__(1024) void fused_row_kernel(
    const float* __restrict__ x,
    const float* __restrict__ Kin, const float* __restrict__ Vin,
    const float* __restrict__ wq, const float* __restrict__ bq,
    const float* __restrict__ wk, const float* __restrict__ bk,
    const float* __restrict__ wv, const float* __restrict__ bv,
    const float* __restrict__ wo, const float* __restrict__ bo,
    const float* __restrict__ w1, const float* __restrict__ b1,
    const float* __restrict__ w2, const float* __restrict__ b2,
    const float* __restrict__ ln1g, const float* __restrict__ ln1b,
    const float* __restrict__ ln2g, const float* __restrict__ ln2b,
    const float* __restrict__ sigmas,
    float* __restrict__ kws, float* __restrict__ vws,
    float* __restrict__ attn_out, float* __restrict__ noiseq_out,
    float* __restrict__ noisez_out, float* __restrict__ r_out,
    uint32_t kq0, uint32_t kq1, uint32_t kk0, uint32_t kk1,
    uint32_t kv0, uint32_t kv1, uint32_t kz0, uint32_t kz1) {
  __shared__ float xs[D_], qs[D_], ksh[D_], vsh[D_], z0s[D_], os[D_];
  __shared__ float att[T_ + 4];
  __shared__ float hs[DFF_];
  __shared__ float4 scq[16][64];   // 16KB  (also reused as [4][256] for FFN1)
  __shared__ float4 sck[16][64];   // 16KB
  __shared__ float4 scv[16][64];   // 16KB
  __shared__ float red[32];
  const int row = blockIdx.x, t = threadIdx.x;
  const int cg = t & 63;           // float4 col group (64 groups x 4 cols)
  const int sl = t >> 6;           // 0..15 K-slice

  if (t < D_) xs[t] = x[row * D_ + t];
  __syncthreads();

  // ---- QKV partials: slice sl covers e in [sl*16, sl*16+16), float4 cols --
  {
    const float4* wqf = (const float4*)wq;
    const float4* wkf = (const float4*)wk;
    const float4* wvf = (const float4*)wv;
    float4 aq = {0,0,0,0}, ak = {0,0,0,0}, av = {0,0,0,0};
    const int e0 = sl * 16;
    #pragma unroll
    for (int e = e0; e < e0 + 16; e++) {
      float xe = xs[e];
      float4 a = wqf[e * 64 + cg];
      float4 b = wkf[e * 64 + cg];
      float4 c = wvf[e * 64 + cg];
      aq.x = fmaf(xe, a.x, aq.x); aq.y = fmaf(xe, a.y, aq.y);
      aq.z = fmaf(xe, a.z, aq.z); aq.w = fmaf(xe, a.w, aq.w);
      ak.x = fmaf(xe, b.x, ak.x); ak.y = fmaf(xe, b.y, ak.y);
      ak.z = fmaf(xe, b.z, ak.z); ak.w = fmaf(xe, b.w, ak.w);
      av.x = fmaf(xe, c.x, av.x); av.y = fmaf(xe, c.y, av.y);
      av.z = fmaf(xe, c.z, av.z); av.w = fmaf(xe, c.w, av.w);
    }
    scq[sl][cg] = aq; sck[sl][cg] = ak; scv[sl][cg] = av;
  }
  __syncthreads();
  // ---- reduce + bias + noise: 3 groups of 256 threads (q,k,v parallel) ----
  if (t < 768) {
    const int m = t >> 8, c = t & 255;
    const float* sc = (m == 0) ? (const float*)scq
                    : (m == 1) ? (const float*)sck : (const float*)scv;
    float s = 0.f;
    #pragma unroll
    for (int j = 0; j < 16; j++) s += sc[j * 256 + c];
    float bias = ((m == 0) ? bq : (m == 1) ? bk : bv)[c];
    float base = bias + s;
    uint32_t i = (uint32_t)row * D_ + c;
    uint32_t a0 = (m == 0) ? kq0 : (m == 1) ? kk0 : kv0;
    uint32_t a1 = (m == 0) ? kq1 : (m == 1) ? kk1 : kv1;
    float val = base + sigmas[m] * jax_normal(a0, a1, i);
    if (m == 0)      { qs[c] = val; noiseq_out[i] = val - base; }
    else if (m == 1) { ksh[c] = val; kws[i] = val; }
    else             { vsh[c] = val; vws[i] = val; }
  }
  __syncthreads();

  // ---- logits: 16 waves, 4 s-values per wave per round, float4 dot ----
  {
    const int wid = t >> 6, lane = t & 63;
    float4 myq = ((const float4*)qs)[lane];
    for (int s0 = wid * 4; s0 <= T_; s0 += 64) {
      #pragma unroll
      for (int j = 0; j < 4; j++) {
        int s = s0 + j;
        if (s <= T_) {
          const float* Krow = (s == T_) ? ksh
                                        : (Kin + ((size_t)row * S_ + s) * D_);
          float4 k4 = ((const float4*)Krow)[lane];
          float rr = myq.x * k4.x + myq.y * k4.y + myq.z * k4.z + myq.w * k4.w;
          #pragma unroll
          for (int off = 32; off > 0; off >>= 1) rr += __shfl_xor(rr, off, 64);
          if (lane == 0) att[s] = rr * 0.0625f;   // / sqrt(256)
        }
      }
    }
  }
  __syncthreads();

  // ---- softmax over 257 logits ----
  {
    float v = (t <= T_) ? att[t] : -INFINITY;
    float mx = blk_max(v, red, t);
    float e = (t <= T_) ? expf(att[t] - mx) : 0.f;
    float sum = blk_sum(e, red, t);
    if (t <= T_) {
      float a = e / sum;
      att[t] = a;
      attn_out[(size_t)row * (T_ + 1) + t] = a;
    }
  }
  __syncthreads();

  // ---- z0 = attn @ Vw: slice sl covers s in [sl*16, sl*16+16) ----
  {
    const float4* Vf = (const float4*)(Vin + (size_t)row * S_ * D_);
    float4 acc = {0,0,0,0};
    const int s0 = sl * 16;
    #pragma unroll
    for (int s = s0; s < s0 + 16; s++) {
      float a = att[s];
      float4 v4 = Vf[s * 64 + cg];
      acc.x = fmaf(a, v4.x, acc.x); acc.y = fmaf(a, v4.y, acc.y);
      acc.z = fmaf(a, v4.z, acc.z); acc.w = fmaf(a, v4.w, acc.w);
    }
    scq[sl][cg] = acc;
  }
  __syncthreads();
  if (t < D_) {
    float s = 0.f;
    #pragma unroll
    for (int j = 0; j < 16; j++) s += ((const float*)scq)[j * 256 + t];
    z0s[t] = s + att[T_] * vsh[t];
  }
  __syncthreads();

  // ---- z = z0 @ wo + bo + noise; y = z + x; LN1 ----
  {
    const float4* wof = (const float4*)wo;
    float4 acc = {0,0,0,0};
    const int e0 = sl * 16;
    #pragma unroll
    for (int e = e0; e < e0 + 16; e++) {
      float ze = z0s[e];
      float4 w4 = wof[e * 64 + cg];
      acc.x = fmaf(ze, w4.x, acc.x); acc.y = fmaf(ze, w4.y, acc.y);
      acc.z = fmaf(ze, w4.z, acc.z); acc.w = fmaf(ze, w4.w, acc.w);
    }
    sck[sl][cg] = acc;
  }
  __syncthreads();
  if (t < D_) {
    float s = 0.f;
    #pragma unroll
    for (int j = 0; j < 16; j++) s += ((const float*)sck)[j * 256 + t];
    float zp = bo[t] + s;
    uint32_t i = (uint32_t)row * D_ + t;
    float zn = zp + sigmas[3] * jax_normal(kz0, kz1, i);
    noisez_out[i] = zn - zp;
    z0s[t] = zn + xs[t];     // reuse z0s as y
  }
  __syncthreads();
  {
    float y = (t < D_) ? z0s[t] : 0.f;
    float mu = blk_sum(y, red, t) * (1.0f / 256.0f);
    float dv = (t < D_) ? (z0s[t] - mu) : 0.f;
    float var = blk_sum(dv * dv, red, t) * (1.0f / 256.0f);
    if (t < D_) os[t] = dv * rsqrtf(var + EPS_) * ln1g[t] + ln1b[t];
  }
  __syncthreads();

  // ---- FFN1: 256 col-groups (f4) x 4 e-slices of 64 ----
  {
    const int cg8 = t & 255, es = t >> 8;
    const float4* w1f = (const float4*)w1;   // [256 rows][256 f4 groups]
    float4 acc = {0,0,0,0};
    const int e0 = es * 64;
    #pragma unroll 8
    for (int e = e0; e < e0 + 64; e++) {
      float oe = os[e];
      float4 w4 = w1f[e * 256 + cg8];
      acc.x = fmaf(oe, w4.x, acc.x); acc.y = fmaf(oe, w4.y, acc.y);
      acc.z = fmaf(oe, w4.z, acc.z); acc.w = fmaf(oe, w4.w, acc.w);
    }
    ((float4*)scq)[es * 256 + cg8] = acc;    // scq as [4][256] f4 (16KB)
  }
  __syncthreads();
  {
    float s = 0.f;
    #pragma unroll
    for (int j = 0; j < 4; j++) s += ((const float*)scq)[j * 1024 + t];
    hs[t] = fmaxf(b1[t] + s, 0.f);
  }
  __syncthreads();

  // ---- FFN2: 64 col-groups (f4) x 16 e-slices of 64 ----
  {
    const float4* w2f = (const float4*)w2;   // [1024 rows][64 f4 groups]
    float4 acc = {0,0,0,0};
    const int e0 = sl * 64;
    #pragma unroll 8
    for (int e = e0; e < e0 + 64; e++) {
      float he = hs[e];
      float4 w4 = w2f[e * 64 + cg];
      acc.x = fmaf(he, w4.x, acc.x); acc.y = fmaf(he, w4.y, acc.y);
      acc.z = fmaf(he, w4.z, acc.z); acc.w = fmaf(he, w4.w, acc.w);
    }
    scv[sl][cg] = acc;
  }
  __syncthreads();
  if (t < D_) {
    float s = 0.f;
    #pragma unroll
    for (int j = 0; j < 16; j++) s += ((const float*)scv)[j * 256 + t];
    z0s[t] = b2[t] + s + os[t];
  }
  __syncthreads();
  {
    float y = (t < D_) ? z0s[t] : 0.f;
    float mu = blk_sum(y, red, t) * (1.0f / 256.0f);
    float dv = (t < D_) ? (z0s[t] - mu) : 0.f;
    float var = blk_sum(dv * dv, red, t) * (1.0f / 256.0f);
    if (t < D_)
      r_out[(size_t)row * D_ + t] = dv * rsqrtf(var + EPS_) * ln2g[t] + ln2b[t];
  }
}

// ---------------- preds = r @ w_out (256x5000x256) ----------------
__global__ __launch_bounds__(256) void preds_kernel(
    const float* __restrict__ r, const float* __restrict__ w_out,
    float* __restrict__ preds) {
  int tid = threadIdx.x;
  int col = blockIdx.x * 250 + tid;
  int rb = blockIdx.y * 16;
  if (tid >= 250) return;
  float acc[16];
  #pragma unroll
  for (int m = 0; m < 16; m++) acc[m] = 0.f;
  #pragma unroll 4
  for (int e = 0; e < D_; e++) {
    float wv = w_out[(size_t)e * VOCAB_ + col];
    #pragma unroll
    for (int m = 0; m < 16; m++)
      acc[m] = fmaf(r[(size_t)(rb + m) * D_ + e], wv, acc[m]);
  }
  #pragma unroll
  for (int m = 0; m < 16; m++)
    preds[(size_t)(rb + m) * VOCAB_ + col] = acc[m];
}

// ---------------- softmax-pick w = probas[y] ----------------
__device__ __forceinline__ float red256_sum(float v, float* red, int tid) {
  red[tid] = v; __syncthreads();
  #pragma unroll
  for (int st = 128; st > 0; st >>= 1) {
    if (tid < st) red[tid] += red[tid + st];
    __syncthreads();
  }
  float r = red[0]; __syncthreads();
  return r;
}
__device__ __forceinline__ float red256_max(float v, float* red, int tid) {
  red[tid] = v; __syncthreads();
  #pragma unroll
  for (int st = 128; st > 0; st >>= 1) {
    if (tid < st) red[tid] = fmaxf(red[tid], red[tid + st]);
    __syncthreads();
  }
  float r = red[0]; __syncthreads();
  return r;
}

__global__ __launch_bounds__(256) void pick_kernel(
    const float* __restrict__ preds, const int* __restrict__ y,
    float* __restrict__ w) {
  __shared__ float red[256];
  int row = blockIdx.x, tid = threadIdx.x;
  const float* pr = preds + (size_t)row * VOCAB_;
  float m = -INFINITY;
  for (int j = tid; j < VOCAB_; j += 256) m = fmaxf(m, pr[j]);
  float mx = red256_max(m, red, tid);
  float s = 0.f;
  for (int j = tid; j < VOCAB_; j += 256) s += expf(pr[j] - mx);
  float sum = red256_sum(s, red, tid);
  if (tid == 0) w[row] = expf(pr[y[row]] - mx) / sum;
}

// ---------------- w_norm + gumbel-max categorical -> i_t ----------------
__global__ __launch_bounds__(256) void cat_kernel(
    const float* __restrict__ w, int* __restrict__ i_t,
    uint32_t kc0, uint32_t kc1) {
  __shared__ float wv[256];
  __shared__ float wn[256];
  int tid = threadIdx.x;
  int b = tid >> 4;
  wv[tid] = w[tid];
  __syncthreads();
  float mx = -INFINITY;
  for (int j = 0; j < 16; j++) mx = fmaxf(mx, wv[b * 16 + j]);
  float ev = expf(wv[tid] - mx);
  wn[tid] = ev;
  __syncthreads();
  float sum = 0.f;
  for (int j = 0; j < 16; j++) sum += wn[b * 16 + j];
  __syncthreads();
  wn[tid] = ev / sum;
  __syncthreads();
  float best = -INFINITY;
  int bi = 0;
  for (int j = 0; j < 16; j++) {
    uint32_t idx = (uint32_t)tid * 16u + (uint32_t)j;
    float g = jax_gumbel(kc0, kc1, idx);
    float sc = g + wn[b * 16 + j];
    if (sc > best) { best = sc; bi = j; }
  }
  i_t[tid] = bi;
}

// ---------------- resample/copy K,V,R (AT roofline: 118.5us, 6.8 TB/s) -----
__global__ __launch_bounds__(256) void resample_kernel(
    const float4* __restrict__ Kin, const float4* __restrict__ Vin,
    const float4* __restrict__ Rin,
    const float4* __restrict__ knew, const float4* __restrict__ vnew,
    const float4* __restrict__ rnew,
    const int* __restrict__ i_t,
    float4* __restrict__ Kout, float4* __restrict__ Vout,
    float4* __restrict__ Rout) {
  uint32_t idx = blockIdx.x * 256u + threadIdx.x;
  uint32_t d4 = idx & 63u;
  uint32_t s  = (idx >> 6) & 511u;
  uint32_t p  = (idx >> 15) & 15u;
  uint32_t b  = idx >> 19;
  const float4* in; const float4* nw; float4* out;
  if (blockIdx.y == 0)      { in = Kin; nw = knew; out = Kout; }
  else if (blockIdx.y == 1) { in = Vin; nw = vnew; out = Vout; }
  else                      { in = Rin; nw = rnew; out = Rout; }
  float4 val;
  if (s > T_) {
    val = in[idx];
  } else {
    uint32_t ip = (uint32_t)i_t[(b << 4) | p];
    if (s == T_) val = nw[(((b << 4) | ip) << 6) | d4];
    else         val = in[(((((b << 4) | ip) << 9) | s) << 6) | d4];
  }
  out[idx] = val;
}

// ---------------- host ----------------
static void compute_subkeys(uint32_t nk[5][2]) {
  const uint32_t k0 = 0u, k1 = 1234u;
  for (uint32_t j = 0; j < 5; j++)
    threefry2x32_(k0, k1, 0u, j, nk[j][0], nk[j][1]);
}

extern "C" void kernel_launch(void* const* d_in, const int* in_sizes, int n_in,
                              void* d_out, int out_size, void* d_ws, size_t ws_size,
                              hipStream_t stream) {
  const float* x    = (const float*)d_in[0];
  const int*   y    = (const int*)d_in[1];
  const float* Kin  = (const float*)d_in[2];
  const float* Vin  = (const float*)d_in[3];
  const float* Rin  = (const float*)d_in[4];
  const float* wq   = (const float*)d_in[5];  const float* bq = (const float*)d_in[6];
  const float* wk   = (const float*)d_in[7];  const float* bk = (const float*)d_in[8];
  const float* wv   = (const float*)d_in[9];  const float* bv = (const float*)d_in[10];
  const float* wo   = (const float*)d_in[11]; const float* bo = (const float*)d_in[12];
  const float* w1   = (const float*)d_in[13]; const float* b1 = (const float*)d_in[14];
  const float* w2   = (const float*)d_in[15]; const float* b2 = (const float*)d_in[16];
  const float* ln1g = (const float*)d_in[17]; const float* ln1b = (const float*)d_in[18];
  const float* ln2g = (const float*)d_in[19]; const float* ln2b = (const float*)d_in[20];
  const float* w_out = (const float*)d_in[21];
  const float* sigmas = (const float*)d_in[22];
  (void)in_sizes; (void)n_in; (void)out_size; (void)ws_size;

  // output layout (flat f32, return order): r, attn, noise_q, noise_z, K, V, R
  float* out        = (float*)d_out;
  float* r_out      = out;
  float* attn_out   = out + 65536;
  float* noiseq_out = out + 131328;
  float* noisez_out = out + 196864;
  float* K_out      = out + 262400;
  float* V_out      = out + 33816832;
  float* R_out      = out + 67371264;

  // workspace layout (floats)
  float* wsf   = (float*)d_ws;
  float* kws   = wsf;                  // 65536
  float* vws   = wsf + 65536;          // 65536
  float* preds = wsf + 131072;         // 1,280,000
  float* wprob = wsf + 1411072;        // 256
  int*   i_t   = (int*)(wsf + 1411328);

  uint32_t nk[5][2];
  compute_subkeys(nk);  // 0=q, 1=k, 2=v, 3=z, 4=categorical

  // Launch 1 (the real one) + 2 idempotent duplicates (INSTRUMENTATION:
  // F = (dur - 266.6)/2). Remove duplicates next round.
  for (int rep = 0; rep < 3; rep++) {
    fused_row_kernel<<<ROWS_, 1024, 0, stream>>>(
        x, Kin, Vin, wq, bq, wk, bk, wv, bv, wo, bo, w1, b1, w2, b2,
        ln1g, ln1b, ln2g, ln2b, sigmas,
        kws, vws, attn_out, noiseq_out, noisez_out, r_out,
        nk[0][0], nk[0][1], nk[1][0], nk[1][1], nk[2][0], nk[2][1],
        nk[3][0], nk[3][1]);
  }
  preds_kernel<<<dim3(20, 16), 256, 0, stream>>>(r_out, w_out, preds);
  pick_kernel<<<ROWS_, 256, 0, stream>>>(preds, y, wprob);
  cat_kernel<<<1, 256, 0, stream>>>(wprob, i_t, nk[4][0], nk[4][1]);
  resample_kernel<<<dim3(32768, 3), 256, 0, stream>>>(
      (const float4*)Kin, (const float4*)Vin, (const float4*)Rin,
      (const float4*)kws, (const float4*)vws, (const float4*)r_out,
      i_t, (float4*)K_out, (float4*)V_out, (float4*)R_out);
}

// Round 8
// 264.817 us; speedup vs baseline: 1.4544x; 1.4281x over previous
//
#include <hip/hip_runtime.h>
#include <stdint.h>
#include <stddef.h>

// ============================================================================
// Ledger (measured): total 266.6 = fused_cold(~110) + resample(118.5, AT
// 6.8TB/s roofline) + preds/pick/cat/gaps(~35). fused_warm = 55.8 (R7).
// R8: fix logits-phase MLP (cold K-stream was shuffle-serialized).
// ============================================================================

// Problem constants (match reference setup_inputs)
#define B_    16
#define P_    16
#define S_    512
#define D_    256
#define DFF_  1024
#define VOCAB_ 5000
#define T_    256
#define ROWS_ 256        // B*P
#define EPS_  1e-6f

#define PARTITIONABLE 1  // jax_threefry_partitionable=True (verified in R1)

// ---------------- threefry2x32 (JAX reference cipher) ----------------
__host__ __device__ __forceinline__ uint32_t rotl32_(uint32_t x, int d) {
  return (x << d) | (x >> (32 - d));
}

__host__ __device__ __forceinline__ void threefry2x32_(uint32_t k0, uint32_t k1,
                                                       uint32_t x0, uint32_t x1,
                                                       uint32_t& o0, uint32_t& o1) {
  uint32_t ks2 = k0 ^ k1 ^ 0x1BD11BDAu;
  x0 += k0; x1 += k1;
  x0 += x1; x1 = rotl32_(x1, 13); x1 ^= x0;
  x0 += x1; x1 = rotl32_(x1, 15); x1 ^= x0;
  x0 += x1; x1 = rotl32_(x1, 26); x1 ^= x0;
  x0 += x1; x1 = rotl32_(x1,  6); x1 ^= x0;
  x0 += k1; x1 += ks2 + 1u;
  x0 += x1; x1 = rotl32_(x1, 17); x1 ^= x0;
  x0 += x1; x1 = rotl32_(x1, 29); x1 ^= x0;
  x0 += x1; x1 = rotl32_(x1, 16); x1 ^= x0;
  x0 += x1; x1 = rotl32_(x1, 24); x1 ^= x0;
  x0 += ks2; x1 += k0 + 2u;
  x0 += x1; x1 = rotl32_(x1, 13); x1 ^= x0;
  x0 += x1; x1 = rotl32_(x1, 15); x1 ^= x0;
  x0 += x1; x1 = rotl32_(x1, 26); x1 ^= x0;
  x0 += x1; x1 = rotl32_(x1,  6); x1 ^= x0;
  x0 += k0; x1 += k1 + 3u;
  x0 += x1; x1 = rotl32_(x1, 17); x1 ^= x0;
  x0 += x1; x1 = rotl32_(x1, 29); x1 ^= x0;
  x0 += x1; x1 = rotl32_(x1, 16); x1 ^= x0;
  x0 += x1; x1 = rotl32_(x1, 24); x1 ^= x0;
  x0 += k1; x1 += ks2 + 4u;
  x0 += x1; x1 = rotl32_(x1, 13); x1 ^= x0;
  x0 += x1; x1 = rotl32_(x1, 15); x1 ^= x0;
  x0 += x1; x1 = rotl32_(x1, 26); x1 ^= x0;
  x0 += x1; x1 = rotl32_(x1,  6); x1 ^= x0;
  x0 += ks2; x1 += k0 + 5u;
  o0 = x0; o1 = x1;
}

__device__ __forceinline__ uint32_t jax_bits(uint32_t k0, uint32_t k1,
                                             uint32_t i) {
#if PARTITIONABLE
  uint32_t o0, o1;
  threefry2x32_(k0, k1, 0u, i, o0, o1);
  return o0 ^ o1;
#else
  return 0u;  // legacy path unused (verified partitionable in R1)
#endif
}

__device__ __forceinline__ float bits_to_u01(uint32_t b) {
  return __uint_as_float((b >> 9) | 0x3F800000u) - 1.0f;
}

// XLA f32 ErfInv (Giles polynomial)
__device__ __forceinline__ float erfinv32(float x) {
  float w = -log1pf(-x * x);
  float p;
  if (w < 5.0f) {
    w -= 2.5f;
    p = 2.81022636e-08f;
    p = fmaf(p, w, 3.43273939e-07f);
    p = fmaf(p, w, -3.5233877e-06f);
    p = fmaf(p, w, -4.39150654e-06f);
    p = fmaf(p, w, 0.00021858087f);
    p = fmaf(p, w, -0.00125372503f);
    p = fmaf(p, w, -0.00417768164f);
    p = fmaf(p, w, 0.246640727f);
    p = fmaf(p, w, 1.50140941f);
  } else {
    w = sqrtf(w) - 3.0f;
    p = -0.000200214257f;
    p = fmaf(p, w, 0.000100950558f);
    p = fmaf(p, w, 0.00134934322f);
    p = fmaf(p, w, -0.00367342844f);
    p = fmaf(p, w, 0.00573950773f);
    p = fmaf(p, w, -0.0076224613f);
    p = fmaf(p, w, 0.00943887047f);
    p = fmaf(p, w, 1.00167406f);
    p = fmaf(p, w, 2.83297682f);
  }
  return p * x;
}

__device__ __forceinline__ float jax_normal(uint32_t k0, uint32_t k1,
                                            uint32_t i) {
  float u01 = bits_to_u01(jax_bits(k0, k1, i));
  const float lo = -0.99999994f;
  float u = __fadd_rn(__fmul_rn(u01, 2.0f), lo);
  u = fmaxf(lo, u);
  return 1.41421356f * erfinv32(u);
}

__device__ __forceinline__ float jax_gumbel(uint32_t k0, uint32_t k1,
                                            uint32_t i) {
  float u01 = bits_to_u01(jax_bits(k0, k1, i));
  const float tiny = 1.17549435e-38f;
  float u = __fadd_rn(__fmul_rn(u01, 1.0f), tiny);
  u = fmaxf(tiny, u);
  return -logf(-logf(u));
}

// ---------------- 1024-thread block reductions (wave shfl + 16-slot LDS) ----
__device__ __forceinline__ float blk_sum(float v, float* red, int tid) {
  #pragma unroll
  for (int off = 32; off > 0; off >>= 1) v += __shfl_xor(v, off, 64);
  if ((tid & 63) == 0) red[tid >> 6] = v;
  __syncthreads();
  if (tid == 0) {
    float s = 0.f;
    #pragma unroll
    for (int i = 0; i < 16; i++) s += red[i];
    red[16] = s;
  }
  __syncthreads();
  float r = red[16];
  __syncthreads();
  return r;
}
__device__ __forceinline__ float blk_max(float v, float* red, int tid) {
  #pragma unroll
  for (int off = 32; off > 0; off >>= 1) v = fmaxf(v, __shfl_xor(v, off, 64));
  if ((tid & 63) == 0) red[tid >> 6] = v;
  __syncthreads();
  if (tid == 0) {
    float s = -INFINITY;
    #pragma unroll
    for (int i = 0; i < 16; i++) s = fmaxf(s, red[i]);
    red[16] = s;
  }
  __syncthreads();
  float r = red[16];
  __syncthreads();
  return r;
}

// ---------------- fused per-row kernel (float4 dot phases) ------------------
__global__ __launch_bounds__(1024) void fused_row_kernel(
    const float* __restrict__ x,
    const float* __restrict__ Kin, const float* __restrict__ Vin,
    const float* __restrict__ wq, const float* __restrict__ bq,
    const float* __restrict__ wk, const float* __restrict__ bk,
    const float* __restrict__ wv, const float* __restrict__ bv,
    const float* __restrict__ wo, const float* __restrict__ bo,
    const float* __restrict__ w1, const float* __restrict__ b1,
    const float* __restrict__ w2, const float* __restrict__ b2,
    const float* __restrict__ ln1g, const float* __restrict__ ln1b,
    const float* __restrict__ ln2g, const float* __restrict__ ln2b,
    const float* __restrict__ sigmas,
    float* __restrict__ kws, float* __restrict__ vws,
    float* __restrict__ attn_out, float* __restrict__ noiseq_out,
    float* __restrict__ noisez_out, float* __restrict__ r_out,
    uint32_t kq0, uint32_t kq1, uint32_t kk0, uint32_t kk1,
    uint32_t kv0, uint32_t kv1, uint32_t kz0, uint32_t kz1) {
  __shared__ __align__(16) float xs[D_], qs[D_], ksh[D_], vsh[D_], z0s[D_], os[D_];
  __shared__ float att[T_ + 4];
  __shared__ __align__(16) float hs[DFF_];
  __shared__ float4 scq[16][64];   // 16KB  (also reused as [4][256] for FFN1)
  __shared__ float4 sck[16][64];   // 16KB
  __shared__ float4 scv[16][64];   // 16KB
  __shared__ float red[32];
  const int row = blockIdx.x, t = threadIdx.x;
  const int cg = t & 63;           // float4 col group (64 groups x 4 cols)
  const int sl = t >> 6;           // 0..15 K-slice

  if (t < D_) xs[t] = x[row * D_ + t];
  __syncthreads();

  // ---- QKV partials: slice sl covers e in [sl*16, sl*16+16), float4 cols --
  {
    const float4* wqf = (const float4*)wq;
    const float4* wkf = (const float4*)wk;
    const float4* wvf = (const float4*)wv;
    float4 aq = {0,0,0,0}, ak = {0,0,0,0}, av = {0,0,0,0};
    const int e0 = sl * 16;
    #pragma unroll
    for (int e = e0; e < e0 + 16; e++) {
      float xe = xs[e];
      float4 a = wqf[e * 64 + cg];
      float4 b = wkf[e * 64 + cg];
      float4 c = wvf[e * 64 + cg];
      aq.x = fmaf(xe, a.x, aq.x); aq.y = fmaf(xe, a.y, aq.y);
      aq.z = fmaf(xe, a.z, aq.z); aq.w = fmaf(xe, a.w, aq.w);
      ak.x = fmaf(xe, b.x, ak.x); ak.y = fmaf(xe, b.y, ak.y);
      ak.z = fmaf(xe, b.z, ak.z); ak.w = fmaf(xe, b.w, ak.w);
      av.x = fmaf(xe, c.x, av.x); av.y = fmaf(xe, c.y, av.y);
      av.z = fmaf(xe, c.z, av.z); av.w = fmaf(xe, c.w, av.w);
    }
    scq[sl][cg] = aq; sck[sl][cg] = ak; scv[sl][cg] = av;
  }
  __syncthreads();
  // ---- reduce + bias + noise: 3 groups of 256 threads (q,k,v parallel) ----
  if (t < 768) {
    const int m = t >> 8, c = t & 255;
    const float* sc = (m == 0) ? (const float*)scq
                    : (m == 1) ? (const float*)sck : (const float*)scv;
    float s = 0.f;
    #pragma unroll
    for (int j = 0; j < 16; j++) s += sc[j * 256 + c];
    float bias = ((m == 0) ? bq : (m == 1) ? bk : bv)[c];
    float base = bias + s;
    uint32_t i = (uint32_t)row * D_ + c;
    uint32_t a0 = (m == 0) ? kq0 : (m == 1) ? kk0 : kv0;
    uint32_t a1 = (m == 0) ? kq1 : (m == 1) ? kk1 : kv1;
    float val = base + sigmas[m] * jax_normal(a0, a1, i);
    if (m == 0)      { qs[c] = val; noiseq_out[i] = val - base; }
    else if (m == 1) { ksh[c] = val; kws[i] = val; }
    else             { vsh[c] = val; vws[i] = val; }
  }
  __syncthreads();

  // ---- logits (R8): 4 threads per K-row, 16 INDEPENDENT f4 loads each ----
  // Per 4-lane group: load j covers 64B contiguous (coalesced); all 16 loads
  // issue before any reduce -> ~256KB in flight per block (vs 16KB before).
  {
    const int sq = t >> 2;        // K row 0..255 (each handled by 4 threads)
    const int qp = t & 3;         // quarter lane
    const float4* qf4 = (const float4*)qs;
    const float4* Krow = (const float4*)(Kin + ((size_t)row * S_ + sq) * D_);
    float rr = 0.f;
    #pragma unroll
    for (int j = 0; j < 16; j++) {
      float4 k4 = Krow[j * 4 + qp];
      float4 q4 = qf4[j * 4 + qp];
      rr += q4.x * k4.x + q4.y * k4.y + q4.z * k4.z + q4.w * k4.w;
    }
    rr += __shfl_xor(rr, 1, 64);
    rr += __shfl_xor(rr, 2, 64);
    if (qp == 0) att[sq] = rr * 0.0625f;   // / sqrt(256)
    // s == T_ (new k in LDS): one wave handles it
    if (t < 64) {
      float4 k4 = ((const float4*)ksh)[t];
      float4 q4 = qf4[t];
      float r2 = q4.x * k4.x + q4.y * k4.y + q4.z * k4.z + q4.w * k4.w;
      #pragma unroll
      for (int off = 32; off > 0; off >>= 1) r2 += __shfl_xor(r2, off, 64);
      if (t == 0) att[T_] = r2 * 0.0625f;
    }
  }
  __syncthreads();

  // ---- softmax over 257 logits ----
  {
    float v = (t <= T_) ? att[t] : -INFINITY;
    float mx = blk_max(v, red, t);
    float e = (t <= T_) ? expf(att[t] - mx) : 0.f;
    float sum = blk_sum(e, red, t);
    if (t <= T_) {
      float a = e / sum;
      att[t] = a;
      attn_out[(size_t)row * (T_ + 1) + t] = a;
    }
  }
  __syncthreads();

  // ---- z0 = attn @ Vw: slice sl covers s in [sl*16, sl*16+16) ----
  {
    const float4* Vf = (const float4*)(Vin + (size_t)row * S_ * D_);
    float4 acc = {0,0,0,0};
    const int s0 = sl * 16;
    #pragma unroll
    for (int s = s0; s < s0 + 16; s++) {
      float a = att[s];
      float4 v4 = Vf[s * 64 + cg];
      acc.x = fmaf(a, v4.x, acc.x); acc.y = fmaf(a, v4.y, acc.y);
      acc.z = fmaf(a, v4.z, acc.z); acc.w = fmaf(a, v4.w, acc.w);
    }
    scq[sl][cg] = acc;
  }
  __syncthreads();
  if (t < D_) {
    float s = 0.f;
    #pragma unroll
    for (int j = 0; j < 16; j++) s += ((const float*)scq)[j * 256 + t];
    z0s[t] = s + att[T_] * vsh[t];
  }
  __syncthreads();

  // ---- z = z0 @ wo + bo + noise; y = z + x; LN1 ----
  {
    const float4* wof = (const float4*)wo;
    float4 acc = {0,0,0,0};
    const int e0 = sl * 16;
    #pragma unroll
    for (int e = e0; e < e0 + 16; e++) {
      float ze = z0s[e];
      float4 w4 = wof[e * 64 + cg];
      acc.x = fmaf(ze, w4.x, acc.x); acc.y = fmaf(ze, w4.y, acc.y);
      acc.z = fmaf(ze, w4.z, acc.z); acc.w = fmaf(ze, w4.w, acc.w);
    }
    sck[sl][cg] = acc;
  }
  __syncthreads();
  if (t < D_) {
    float s = 0.f;
    #pragma unroll
    for (int j = 0; j < 16; j++) s += ((const float*)sck)[j * 256 + t];
    float zp = bo[t] + s;
    uint32_t i = (uint32_t)row * D_ + t;
    float zn = zp + sigmas[3] * jax_normal(kz0, kz1, i);
    noisez_out[i] = zn - zp;
    z0s[t] = zn + xs[t];     // reuse z0s as y
  }
  __syncthreads();
  {
    float y = (t < D_) ? z0s[t] : 0.f;
    float mu = blk_sum(y, red, t) * (1.0f / 256.0f);
    float dv = (t < D_) ? (z0s[t] - mu) : 0.f;
    float var = blk_sum(dv * dv, red, t) * (1.0f / 256.0f);
    if (t < D_) os[t] = dv * rsqrtf(var + EPS_) * ln1g[t] + ln1b[t];
  }
  __syncthreads();

  // ---- FFN1: 256 col-groups (f4) x 4 e-slices of 64 ----
  {
    const int cg8 = t & 255, es = t >> 8;
    const float4* w1f = (const float4*)w1;   // [256 rows][256 f4 groups]
    float4 acc = {0,0,0,0};
    const int e0 = es * 64;
    #pragma unroll 8
    for (int e = e0; e < e0 + 64; e++) {
      float oe = os[e];
      float4 w4 = w1f[e * 256 + cg8];
      acc.x = fmaf(oe, w4.x, acc.x); acc.y = fmaf(oe, w4.y, acc.y);
      acc.z = fmaf(oe, w4.z, acc.z); acc.w = fmaf(oe, w4.w, acc.w);
    }
    ((float4*)scq)[es * 256 + cg8] = acc;    // scq as [4][256] f4 (16KB)
  }
  __syncthreads();
  {
    float s = 0.f;
    #pragma unroll
    for (int j = 0; j < 4; j++) s += ((const float*)scq)[j * 1024 + t];
    hs[t] = fmaxf(b1[t] + s, 0.f);
  }
  __syncthreads();

  // ---- FFN2: 64 col-groups (f4) x 16 e-slices of 64 ----
  {
    const float4* w2f = (const float4*)w2;   // [1024 rows][64 f4 groups]
    float4 acc = {0,0,0,0};
    const int e0 = sl * 64;
    #pragma unroll 8
    for (int e = e0; e < e0 + 64; e++) {
      float he = hs[e];
      float4 w4 = w2f[e * 64 + cg];
      acc.x = fmaf(he, w4.x, acc.x); acc.y = fmaf(he, w4.y, acc.y);
      acc.z = fmaf(he, w4.z, acc.z); acc.w = fmaf(he, w4.w, acc.w);
    }
    scv[sl][cg] = acc;
  }
  __syncthreads();
  if (t < D_) {
    float s = 0.f;
    #pragma unroll
    for (int j = 0; j < 16; j++) s += ((const float*)scv)[j * 256 + t];
    z0s[t] = b2[t] + s + os[t];
  }
  __syncthreads();
  {
    float y = (t < D_) ? z0s[t] : 0.f;
    float mu = blk_sum(y, red, t) * (1.0f / 256.0f);
    float dv = (t < D_) ? (z0s[t] - mu) : 0.f;
    float var = blk_sum(dv * dv, red, t) * (1.0f / 256.0f);
    if (t < D_)
      r_out[(size_t)row * D_ + t] = dv * rsqrtf(var + EPS_) * ln2g[t] + ln2b[t];
  }
}

// ---------------- preds = r @ w_out (256x5000x256) ----------------
__global__ __launch_bounds__(256) void preds_kernel(
    const float* __restrict__ r, const float* __restrict__ w_out,
    float* __restrict__ preds) {
  int tid = threadIdx.x;
  int col = blockIdx.x * 250 + tid;
  int rb = blockIdx.y * 16;
  if (tid >= 250) return;
  float acc[16];
  #pragma unroll
  for (int m = 0; m < 16; m++) acc[m] = 0.f;
  #pragma unroll 4
  for (int e = 0; e < D_; e++) {
    float wv = w_out[(size_t)e * VOCAB_ + col];
    #pragma unroll
    for (int m = 0; m < 16; m++)
      acc[m] = fmaf(r[(size_t)(rb + m) * D_ + e], wv, acc[m]);
  }
  #pragma unroll
  for (int m = 0; m < 16; m++)
    preds[(size_t)(rb + m) * VOCAB_ + col] = acc[m];
}

// ---------------- softmax-pick w = probas[y] ----------------
__device__ __forceinline__ float red256_sum(float v, float* red, int tid) {
  red[tid] = v; __syncthreads();
  #pragma unroll
  for (int st = 128; st > 0; st >>= 1) {
    if (tid < st) red[tid] += red[tid + st];
    __syncthreads();
  }
  float r = red[0]; __syncthreads();
  return r;
}
__device__ __forceinline__ float red256_max(float v, float* red, int tid) {
  red[tid] = v; __syncthreads();
  #pragma unroll
  for (int st = 128; st > 0; st >>= 1) {
    if (tid < st) red[tid] = fmaxf(red[tid], red[tid + st]);
    __syncthreads();
  }
  float r = red[0]; __syncthreads();
  return r;
}

__global__ __launch_bounds__(256) void pick_kernel(
    const float* __restrict__ preds, const int* __restrict__ y,
    float* __restrict__ w) {
  __shared__ float red[256];
  int row = blockIdx.x, tid = threadIdx.x;
  const float* pr = preds + (size_t)row * VOCAB_;
  float m = -INFINITY;
  for (int j = tid; j < VOCAB_; j += 256) m = fmaxf(m, pr[j]);
  float mx = red256_max(m, red, tid);
  float s = 0.f;
  for (int j = tid; j < VOCAB_; j += 256) s += expf(pr[j] - mx);
  float sum = red256_sum(s, red, tid);
  if (tid == 0) w[row] = expf(pr[y[row]] - mx) / sum;
}

// ---------------- w_norm + gumbel-max categorical -> i_t ----------------
__global__ __launch_bounds__(256) void cat_kernel(
    const float* __restrict__ w, int* __restrict__ i_t,
    uint32_t kc0, uint32_t kc1) {
  __shared__ float wv[256];
  __shared__ float wn[256];
  int tid = threadIdx.x;
  int b = tid >> 4;
  wv[tid] = w[tid];
  __syncthreads();
  float mx = -INFINITY;
  for (int j = 0; j < 16; j++) mx = fmaxf(mx, wv[b * 16 + j]);
  float ev = expf(wv[tid] - mx);
  wn[tid] = ev;
  __syncthreads();
  float sum = 0.f;
  for (int j = 0; j < 16; j++) sum += wn[b * 16 + j];
  __syncthreads();
  wn[tid] = ev / sum;
  __syncthreads();
  float best = -INFINITY;
  int bi = 0;
  for (int j = 0; j < 16; j++) {
    uint32_t idx = (uint32_t)tid * 16u + (uint32_t)j;
    float g = jax_gumbel(kc0, kc1, idx);
    float sc = g + wn[b * 16 + j];
    if (sc > best) { best = sc; bi = j; }
  }
  i_t[tid] = bi;
}

// ---------------- resample/copy K,V,R (AT roofline: 118.5us, 6.8 TB/s) -----
__global__ __launch_bounds__(256) void resample_kernel(
    const float4* __restrict__ Kin, const float4* __restrict__ Vin,
    const float4* __restrict__ Rin,
    const float4* __restrict__ knew, const float4* __restrict__ vnew,
    const float4* __restrict__ rnew,
    const int* __restrict__ i_t,
    float4* __restrict__ Kout, float4* __restrict__ Vout,
    float4* __restrict__ Rout) {
  uint32_t idx = blockIdx.x * 256u + threadIdx.x;
  uint32_t d4 = idx & 63u;
  uint32_t s  = (idx >> 6) & 511u;
  uint32_t p  = (idx >> 15) & 15u;
  uint32_t b  = idx >> 19;
  const float4* in; const float4* nw; float4* out;
  if (blockIdx.y == 0)      { in = Kin; nw = knew; out = Kout; }
  else if (blockIdx.y == 1) { in = Vin; nw = vnew; out = Vout; }
  else                      { in = Rin; nw = rnew; out = Rout; }
  float4 val;
  if (s > T_) {
    val = in[idx];
  } else {
    uint32_t ip = (uint32_t)i_t[(b << 4) | p];
    if (s == T_) val = nw[(((b << 4) | ip) << 6) | d4];
    else         val = in[(((((b << 4) | ip) << 9) | s) << 6) | d4];
  }
  out[idx] = val;
}

// ---------------- host ----------------
static void compute_subkeys(uint32_t nk[5][2]) {
  const uint32_t k0 = 0u, k1 = 1234u;
  for (uint32_t j = 0; j < 5; j++)
    threefry2x32_(k0, k1, 0u, j, nk[j][0], nk[j][1]);
}

extern "C" void kernel_launch(void* const* d_in, const int* in_sizes, int n_in,
                              void* d_out, int out_size, void* d_ws, size_t ws_size,
                              hipStream_t stream) {
  const float* x    = (const float*)d_in[0];
  const int*   y    = (const int*)d_in[1];
  const float* Kin  = (const float*)d_in[2];
  const float* Vin  = (const float*)d_in[3];
  const float* Rin  = (const float*)d_in[4];
  const float* wq   = (const float*)d_in[5];  const float* bq = (const float*)d_in[6];
  const float* wk   = (const float*)d_in[7];  const float* bk = (const float*)d_in[8];
  const float* wv   = (const float*)d_in[9];  const float* bv = (const float*)d_in[10];
  const float* wo   = (const float*)d_in[11]; const float* bo = (const float*)d_in[12];
  const float* w1   = (const float*)d_in[13]; const float* b1 = (const float*)d_in[14];
  const float* w2   = (const float*)d_in[15]; const float* b2 = (const float*)d_in[16];
  const float* ln1g = (const float*)d_in[17]; const float* ln1b = (const float*)d_in[18];
  const float* ln2g = (const float*)d_in[19]; const float* ln2b = (const float*)d_in[20];
  const float* w_out = (const float*)d_in[21];
  const float* sigmas = (const float*)d_in[22];
  (void)in_sizes; (void)n_in; (void)out_size; (void)ws_size;

  // output layout (flat f32, return order): r, attn, noise_q, noise_z, K, V, R
  float* out        = (float*)d_out;
  float* r_out      = out;
  float* attn_out   = out + 65536;
  float* noiseq_out = out + 131328;
  float* noisez_out = out + 196864;
  float* K_out      = out + 262400;
  float* V_out      = out + 33816832;
  float* R_out      = out + 67371264;

  // workspace layout (floats)
  float* wsf   = (float*)d_ws;
  float* kws   = wsf;                  // 65536
  float* vws   = wsf + 65536;          // 65536
  float* preds = wsf + 131072;         // 1,280,000
  float* wprob = wsf + 1411072;        // 256
  int*   i_t   = (int*)(wsf + 1411328);

  uint32_t nk[5][2];
  compute_subkeys(nk);  // 0=q, 1=k, 2=v, 3=z, 4=categorical

  fused_row_kernel<<<ROWS_, 1024, 0, stream>>>(
      x, Kin, Vin, wq, bq, wk, bk, wv, bv, wo, bo, w1, b1, w2, b2,
      ln1g, ln1b, ln2g, ln2b, sigmas,
      kws, vws, attn_out, noiseq_out, noisez_out, r_out,
      nk[0][0], nk[0][1], nk[1][0], nk[1][1], nk[2][0], nk[2][1],
      nk[3][0], nk[3][1]);
  preds_kernel<<<dim3(20, 16), 256, 0, stream>>>(r_out, w_out, preds);
  pick_kernel<<<ROWS_, 256, 0, stream>>>(preds, y, wprob);
  cat_kernel<<<1, 256, 0, stream>>>(wprob, i_t, nk[4][0], nk[4][1]);
  resample_kernel<<<dim3(32768, 3), 256, 0, stream>>>(
      (const float4*)Kin, (const float4*)Vin, (const float4*)Rin,
      (const float4*)kws, (const float4*)vws, (const float4*)r_out,
      i_t, (float4*)K_out, (float4*)V_out, (float4*)R_out);
}

// Round 9
// 256.667 us; speedup vs baseline: 1.5006x; 1.0318x over previous
//
#include <hip/hip_runtime.h>
#include <stdint.h>
#include <stddef.h>

// ============================================================================
// Ledger (measured): resample 805MB = 118.5us @6.8TB/s (roofline). fused_warm
// = 55.8us. Total 266.6 => F_cold + preds+pick+cat + 4 gaps = 148.
// R9: 4-kernel pipeline. K2 = preds-partials (+tail-copy 503MB, no deps,
// hides preds/pick compute under copy BW). K3 = combine+cat. K4 = head-
// resample (302MB). Fused kernel byte-identical to R8.
// ============================================================================

#define B_    16
#define P_    16
#define S_    512
#define D_    256
#define DFF_  1024
#define VOCAB_ 5000
#define T_    256
#define ROWS_ 256        // B*P
#define EPS_  1e-6f

#define PARTITIONABLE 1  // verified in R1

// ---------------- threefry2x32 (JAX reference cipher) ----------------
__host__ __device__ __forceinline__ uint32_t rotl32_(uint32_t x, int d) {
  return (x << d) | (x >> (32 - d));
}

__host__ __device__ __forceinline__ void threefry2x32_(uint32_t k0, uint32_t k1,
                                                       uint32_t x0, uint32_t x1,
                                                       uint32_t& o0, uint32_t& o1) {
  uint32_t ks2 = k0 ^ k1 ^ 0x1BD11BDAu;
  x0 += k0; x1 += k1;
  x0 += x1; x1 = rotl32_(x1, 13); x1 ^= x0;
  x0 += x1; x1 = rotl32_(x1, 15); x1 ^= x0;
  x0 += x1; x1 = rotl32_(x1, 26); x1 ^= x0;
  x0 += x1; x1 = rotl32_(x1,  6); x1 ^= x0;
  x0 += k1; x1 += ks2 + 1u;
  x0 += x1; x1 = rotl32_(x1, 17); x1 ^= x0;
  x0 += x1; x1 = rotl32_(x1, 29); x1 ^= x0;
  x0 += x1; x1 = rotl32_(x1, 16); x1 ^= x0;
  x0 += x1; x1 = rotl32_(x1, 24); x1 ^= x0;
  x0 += ks2; x1 += k0 + 2u;
  x0 += x1; x1 = rotl32_(x1, 13); x1 ^= x0;
  x0 += x1; x1 = rotl32_(x1, 15); x1 ^= x0;
  x0 += x1; x1 = rotl32_(x1, 26); x1 ^= x0;
  x0 += x1; x1 = rotl32_(x1,  6); x1 ^= x0;
  x0 += k0; x1 += k1 + 3u;
  x0 += x1; x1 = rotl32_(x1, 17); x1 ^= x0;
  x0 += x1; x1 = rotl32_(x1, 29); x1 ^= x0;
  x0 += x1; x1 = rotl32_(x1, 16); x1 ^= x0;
  x0 += x1; x1 = rotl32_(x1, 24); x1 ^= x0;
  x0 += k1; x1 += ks2 + 4u;
  x0 += x1; x1 = rotl32_(x1, 13); x1 ^= x0;
  x0 += x1; x1 = rotl32_(x1, 15); x1 ^= x0;
  x0 += x1; x1 = rotl32_(x1, 26); x1 ^= x0;
  x0 += x1; x1 = rotl32_(x1,  6); x1 ^= x0;
  x0 += ks2; x1 += k0 + 5u;
  o0 = x0; o1 = x1;
}

__device__ __forceinline__ uint32_t jax_bits(uint32_t k0, uint32_t k1,
                                             uint32_t i) {
#if PARTITIONABLE
  uint32_t o0, o1;
  threefry2x32_(k0, k1, 0u, i, o0, o1);
  return o0 ^ o1;
#else
  return 0u;
#endif
}

__device__ __forceinline__ float bits_to_u01(uint32_t b) {
  return __uint_as_float((b >> 9) | 0x3F800000u) - 1.0f;
}

// XLA f32 ErfInv (Giles polynomial)
__device__ __forceinline__ float erfinv32(float x) {
  float w = -log1pf(-x * x);
  float p;
  if (w < 5.0f) {
    w -= 2.5f;
    p = 2.81022636e-08f;
    p = fmaf(p, w, 3.43273939e-07f);
    p = fmaf(p, w, -3.5233877e-06f);
    p = fmaf(p, w, -4.39150654e-06f);
    p = fmaf(p, w, 0.00021858087f);
    p = fmaf(p, w, -0.00125372503f);
    p = fmaf(p, w, -0.00417768164f);
    p = fmaf(p, w, 0.246640727f);
    p = fmaf(p, w, 1.50140941f);
  } else {
    w = sqrtf(w) - 3.0f;
    p = -0.000200214257f;
    p = fmaf(p, w, 0.000100950558f);
    p = fmaf(p, w, 0.00134934322f);
    p = fmaf(p, w, -0.00367342844f);
    p = fmaf(p, w, 0.00573950773f);
    p = fmaf(p, w, -0.0076224613f);
    p = fmaf(p, w, 0.00943887047f);
    p = fmaf(p, w, 1.00167406f);
    p = fmaf(p, w, 2.83297682f);
  }
  return p * x;
}

__device__ __forceinline__ float jax_normal(uint32_t k0, uint32_t k1,
                                            uint32_t i) {
  float u01 = bits_to_u01(jax_bits(k0, k1, i));
  const float lo = -0.99999994f;
  float u = __fadd_rn(__fmul_rn(u01, 2.0f), lo);
  u = fmaxf(lo, u);
  return 1.41421356f * erfinv32(u);
}

__device__ __forceinline__ float jax_gumbel(uint32_t k0, uint32_t k1,
                                            uint32_t i) {
  float u01 = bits_to_u01(jax_bits(k0, k1, i));
  const float tiny = 1.17549435e-38f;
  float u = __fadd_rn(__fmul_rn(u01, 1.0f), tiny);
  u = fmaxf(tiny, u);
  return -logf(-logf(u));
}

// ---------------- 1024-thread block reductions ----------------
__device__ __forceinline__ float blk_sum(float v, float* red, int tid) {
  #pragma unroll
  for (int off = 32; off > 0; off >>= 1) v += __shfl_xor(v, off, 64);
  if ((tid & 63) == 0) red[tid >> 6] = v;
  __syncthreads();
  if (tid == 0) {
    float s = 0.f;
    #pragma unroll
    for (int i = 0; i < 16; i++) s += red[i];
    red[16] = s;
  }
  __syncthreads();
  float r = red[16];
  __syncthreads();
  return r;
}
__device__ __forceinline__ float blk_max(float v, float* red, int tid) {
  #pragma unroll
  for (int off = 32; off > 0; off >>= 1) v = fmaxf(v, __shfl_xor(v, off, 64));
  if ((tid & 63) == 0) red[tid >> 6] = v;
  __syncthreads();
  if (tid == 0) {
    float s = -INFINITY;
    #pragma unroll
    for (int i = 0; i < 16; i++) s = fmaxf(s, red[i]);
    red[16] = s;
  }
  __syncthreads();
  float r = red[16];
  __syncthreads();
  return r;
}

// ---------------- K1: fused per-row kernel (identical to R8) ----------------
__global__ __launch_bounds__(1024) void fused_row_kernel(
    const float* __restrict__ x,
    const float* __restrict__ Kin, const float* __restrict__ Vin,
    const float* __restrict__ wq, const float* __restrict__ bq,
    const float* __restrict__ wk, const float* __restrict__ bk,
    const float* __restrict__ wv, const float* __restrict__ bv,
    const float* __restrict__ wo, const float* __restrict__ bo,
    const float* __restrict__ w1, const float* __restrict__ b1,
    const float* __restrict__ w2, const float* __restrict__ b2,
    const float* __restrict__ ln1g, const float* __restrict__ ln1b,
    const float* __restrict__ ln2g, const float* __restrict__ ln2b,
    const float* __restrict__ sigmas,
    float* __restrict__ kws, float* __restrict__ vws,
    float* __restrict__ attn_out, float* __restrict__ noiseq_out,
    float* __restrict__ noisez_out, float* __restrict__ r_out,
    uint32_t kq0, uint32_t kq1, uint32_t kk0, uint32_t kk1,
    uint32_t kv0, uint32_t kv1, uint32_t kz0, uint32_t kz1) {
  __shared__ __align__(16) float xs[D_], qs[D_], ksh[D_], vsh[D_], z0s[D_], os[D_];
  __shared__ float att[T_ + 4];
  __shared__ __align__(16) float hs[DFF_];
  __shared__ float4 scq[16][64];
  __shared__ float4 sck[16][64];
  __shared__ float4 scv[16][64];
  __shared__ float red[32];
  const int row = blockIdx.x, t = threadIdx.x;
  const int cg = t & 63;
  const int sl = t >> 6;

  if (t < D_) xs[t] = x[row * D_ + t];
  __syncthreads();

  {
    const float4* wqf = (const float4*)wq;
    const float4* wkf = (const float4*)wk;
    const float4* wvf = (const float4*)wv;
    float4 aq = {0,0,0,0}, ak = {0,0,0,0}, av = {0,0,0,0};
    const int e0 = sl * 16;
    #pragma unroll
    for (int e = e0; e < e0 + 16; e++) {
      float xe = xs[e];
      float4 a = wqf[e * 64 + cg];
      float4 b = wkf[e * 64 + cg];
      float4 c = wvf[e * 64 + cg];
      aq.x = fmaf(xe, a.x, aq.x); aq.y = fmaf(xe, a.y, aq.y);
      aq.z = fmaf(xe, a.z, aq.z); aq.w = fmaf(xe, a.w, aq.w);
      ak.x = fmaf(xe, b.x, ak.x); ak.y = fmaf(xe, b.y, ak.y);
      ak.z = fmaf(xe, b.z, ak.z); ak.w = fmaf(xe, b.w, ak.w);
      av.x = fmaf(xe, c.x, av.x); av.y = fmaf(xe, c.y, av.y);
      av.z = fmaf(xe, c.z, av.z); av.w = fmaf(xe, c.w, av.w);
    }
    scq[sl][cg] = aq; sck[sl][cg] = ak; scv[sl][cg] = av;
  }
  __syncthreads();
  if (t < 768) {
    const int m = t >> 8, c = t & 255;
    const float* sc = (m == 0) ? (const float*)scq
                    : (m == 1) ? (const float*)sck : (const float*)scv;
    float s = 0.f;
    #pragma unroll
    for (int j = 0; j < 16; j++) s += sc[j * 256 + c];
    float bias = ((m == 0) ? bq : (m == 1) ? bk : bv)[c];
    float base = bias + s;
    uint32_t i = (uint32_t)row * D_ + c;
    uint32_t a0 = (m == 0) ? kq0 : (m == 1) ? kk0 : kv0;
    uint32_t a1 = (m == 0) ? kq1 : (m == 1) ? kk1 : kv1;
    float val = base + sigmas[m] * jax_normal(a0, a1, i);
    if (m == 0)      { qs[c] = val; noiseq_out[i] = val - base; }
    else if (m == 1) { ksh[c] = val; kws[i] = val; }
    else             { vsh[c] = val; vws[i] = val; }
  }
  __syncthreads();

  {
    const int sq = t >> 2;
    const int qp = t & 3;
    const float4* qf4 = (const float4*)qs;
    const float4* Krow = (const float4*)(Kin + ((size_t)row * S_ + sq) * D_);
    float rr = 0.f;
    #pragma unroll
    for (int j = 0; j < 16; j++) {
      float4 k4 = Krow[j * 4 + qp];
      float4 q4 = qf4[j * 4 + qp];
      rr += q4.x * k4.x + q4.y * k4.y + q4.z * k4.z + q4.w * k4.w;
    }
    rr += __shfl_xor(rr, 1, 64);
    rr += __shfl_xor(rr, 2, 64);
    if (qp == 0) att[sq] = rr * 0.0625f;
    if (t < 64) {
      float4 k4 = ((const float4*)ksh)[t];
      float4 q4 = qf4[t];
      float r2 = q4.x * k4.x + q4.y * k4.y + q4.z * k4.z + q4.w * k4.w;
      #pragma unroll
      for (int off = 32; off > 0; off >>= 1) r2 += __shfl_xor(r2, off, 64);
      if (t == 0) att[T_] = r2 * 0.0625f;
    }
  }
  __syncthreads();

  {
    float v = (t <= T_) ? att[t] : -INFINITY;
    float mx = blk_max(v, red, t);
    float e = (t <= T_) ? expf(att[t] - mx) : 0.f;
    float sum = blk_sum(e, red, t);
    if (t <= T_) {
      float a = e / sum;
      att[t] = a;
      attn_out[(size_t)row * (T_ + 1) + t] = a;
    }
  }
  __syncthreads();

  {
    const float4* Vf = (const float4*)(Vin + (size_t)row * S_ * D_);
    float4 acc = {0,0,0,0};
    const int s0 = sl * 16;
    #pragma unroll
    for (int s = s0; s < s0 + 16; s++) {
      float a = att[s];
      float4 v4 = Vf[s * 64 + cg];
      acc.x = fmaf(a, v4.x, acc.x); acc.y = fmaf(a, v4.y, acc.y);
      acc.z = fmaf(a, v4.z, acc.z); acc.w = fmaf(a, v4.w, acc.w);
    }
    scq[sl][cg] = acc;
  }
  __syncthreads();
  if (t < D_) {
    float s = 0.f;
    #pragma unroll
    for (int j = 0; j < 16; j++) s += ((const float*)scq)[j * 256 + t];
    z0s[t] = s + att[T_] * vsh[t];
  }
  __syncthreads();

  {
    const float4* wof = (const float4*)wo;
    float4 acc = {0,0,0,0};
    const int e0 = sl * 16;
    #pragma unroll
    for (int e = e0; e < e0 + 16; e++) {
      float ze = z0s[e];
      float4 w4 = wof[e * 64 + cg];
      acc.x = fmaf(ze, w4.x, acc.x); acc.y = fmaf(ze, w4.y, acc.y);
      acc.z = fmaf(ze, w4.z, acc.z); acc.w = fmaf(ze, w4.w, acc.w);
    }
    sck[sl][cg] = acc;
  }
  __syncthreads();
  if (t < D_) {
    float s = 0.f;
    #pragma unroll
    for (int j = 0; j < 16; j++) s += ((const float*)sck)[j * 256 + t];
    float zp = bo[t] + s;
    uint32_t i = (uint32_t)row * D_ + t;
    float zn = zp + sigmas[3] * jax_normal(kz0, kz1, i);
    noisez_out[i] = zn - zp;
    z0s[t] = zn + xs[t];
  }
  __syncthreads();
  {
    float y = (t < D_) ? z0s[t] : 0.f;
    float mu = blk_sum(y, red, t) * (1.0f / 256.0f);
    float dv = (t < D_) ? (z0s[t] - mu) : 0.f;
    float var = blk_sum(dv * dv, red, t) * (1.0f / 256.0f);
    if (t < D_) os[t] = dv * rsqrtf(var + EPS_) * ln1g[t] + ln1b[t];
  }
  __syncthreads();

  {
    const int cg8 = t & 255, es = t >> 8;
    const float4* w1f = (const float4*)w1;
    float4 acc = {0,0,0,0};
    const int e0 = es * 64;
    #pragma unroll 8
    for (int e = e0; e < e0 + 64; e++) {
      float oe = os[e];
      float4 w4 = w1f[e * 256 + cg8];
      acc.x = fmaf(oe, w4.x, acc.x); acc.y = fmaf(oe, w4.y, acc.y);
      acc.z = fmaf(oe, w4.z, acc.z); acc.w = fmaf(oe, w4.w, acc.w);
    }
    ((float4*)scq)[es * 256 + cg8] = acc;
  }
  __syncthreads();
  {
    float s = 0.f;
    #pragma unroll
    for (int j = 0; j < 4; j++) s += ((const float*)scq)[j * 1024 + t];
    hs[t] = fmaxf(b1[t] + s, 0.f);
  }
  __syncthreads();

  {
    const float4* w2f = (const float4*)w2;
    float4 acc = {0,0,0,0};
    const int e0 = sl * 64;
    #pragma unroll 8
    for (int e = e0; e < e0 + 64; e++) {
      float he = hs[e];
      float4 w4 = w2f[e * 64 + cg];
      acc.x = fmaf(he, w4.x, acc.x); acc.y = fmaf(he, w4.y, acc.y);
      acc.z = fmaf(he, w4.z, acc.z); acc.w = fmaf(he, w4.w, acc.w);
    }
    scv[sl][cg] = acc;
  }
  __syncthreads();
  if (t < D_) {
    float s = 0.f;
    #pragma unroll
    for (int j = 0; j < 16; j++) s += ((const float*)scv)[j * 256 + t];
    z0s[t] = b2[t] + s + os[t];
  }
  __syncthreads();
  {
    float y = (t < D_) ? z0s[t] : 0.f;
    float mu = blk_sum(y, red, t) * (1.0f / 256.0f);
    float dv = (t < D_) ? (z0s[t] - mu) : 0.f;
    float var = blk_sum(dv * dv, red, t) * (1.0f / 256.0f);
    if (t < D_)
      r_out[(size_t)row * D_ + t] = dv * rsqrtf(var + EPS_) * ln2g[t] + ln2b[t];
  }
}

// ---------------- K2: preds-partials + tail-copy ----------------
// blocks [0,320): preds partial softmax stats for (rowchunk, colchunk).
// blocks [320, 320+3060): tail copy s in [257,511] of K,V,R (503 MB, no deps).
#define PREDS_BLOCKS 320
#define TAIL_BLOCKS_PER_TENSOR 1020   // 255 s-rows x 4 chunks of 64 bp
__global__ __launch_bounds__(256) void preds_tail_kernel(
    const float* __restrict__ r, const float* __restrict__ w_out,
    const int* __restrict__ y,
    const float4* __restrict__ Kin, const float4* __restrict__ Vin,
    const float4* __restrict__ Rin,
    float4* __restrict__ Kout, float4* __restrict__ Vout,
    float4* __restrict__ Rout,
    float* __restrict__ pm, float* __restrict__ ps, float* __restrict__ pe) {
  const int bx = blockIdx.x, tid = threadIdx.x;
  if (bx >= PREDS_BLOCKS) {
    // ---- tail copy role ----
    const int c = bx - PREDS_BLOCKS;
    const int tau = c / TAIL_BLOCKS_PER_TENSOR;
    const int c2 = c - tau * TAIL_BLOCKS_PER_TENSOR;
    const uint32_t s = 257u + (uint32_t)(c2 >> 2);
    const uint32_t q = (uint32_t)(c2 & 3);
    const float4* in = (tau == 0) ? Kin : (tau == 1) ? Vin : Rin;
    float4* out      = (tau == 0) ? Kout : (tau == 1) ? Vout : Rout;
    #pragma unroll
    for (int k = 0; k < 16; k++) {
      uint32_t local = (uint32_t)k * 256u + (uint32_t)tid;
      uint32_t bp = (q << 6) | (local >> 6);
      uint32_t d4 = local & 63u;
      uint32_t f4i = (bp << 15) | (s << 6) | d4;
      out[f4i] = in[f4i];
    }
    return;
  }
  // ---- preds-partial role: rowchunk rc (16 rows), colchunk cc (250 cols) ----
  __shared__ float sm[16][264];
  __shared__ float pr16[16][17];
  __shared__ float pms[16], pss[16], eys[16];
  __shared__ int yvs[16];
  const int rc = bx / 20, cc = bx - rc * 20;
  const int rb = rc * 16;
  const int col = cc * 250 + tid;
  const int colc = (col < VOCAB_) ? col : (VOCAB_ - 1);
  if (tid < 16) { yvs[tid] = y[rb + tid]; eys[tid] = 0.f; }
  float acc[16];
  #pragma unroll
  for (int m = 0; m < 16; m++) acc[m] = 0.f;
  #pragma unroll 4
  for (int e = 0; e < D_; e++) {
    float wv = w_out[(size_t)e * VOCAB_ + colc];
    #pragma unroll
    for (int m = 0; m < 16; m++)
      acc[m] = fmaf(r[(size_t)(rb + m) * D_ + e], wv, acc[m]);
  }
  const bool act = (tid < 250);
  #pragma unroll
  for (int m = 0; m < 16; m++) sm[m][tid] = act ? acc[m] : -INFINITY;
  __syncthreads();
  // per-row max: 16 threads per row
  {
    const int rr = tid >> 4, j = tid & 15;
    float mx = -INFINITY;
    for (int c = j; c < 256; c += 16) mx = fmaxf(mx, sm[rr][c]);
    pr16[rr][j] = mx;
  }
  __syncthreads();
  if (tid < 16) {
    float mx = -INFINITY;
    #pragma unroll
    for (int j = 0; j < 16; j++) mx = fmaxf(mx, pr16[tid][j]);
    pms[tid] = mx;
  }
  __syncthreads();
  // per-row sum of exp
  {
    const int rr = tid >> 4, j = tid & 15;
    float mb = pms[rr];
    float sum = 0.f;
    for (int c = j; c < 256; c += 16) sum += expf(sm[rr][c] - mb);  // exp(-inf)=0
    pr16[rr][j] = sum;
  }
  __syncthreads();
  if (tid < 16) {
    float s = 0.f;
    #pragma unroll
    for (int j = 0; j < 16; j++) s += pr16[tid][j];
    pss[tid] = s;
  }
  __syncthreads();
  // e_y contribution (at most one col matches per row)
  if (act) {
    #pragma unroll
    for (int m = 0; m < 16; m++)
      if (col == yvs[m]) eys[m] = expf(acc[m] - pms[m]);
  }
  __syncthreads();
  if (tid < 16) {
    pm[(rb + tid) * 20 + cc] = pms[tid];
    ps[(rb + tid) * 20 + cc] = pss[tid];
    pe[(rb + tid) * 20 + cc] = eys[tid];
  }
}

// ---------------- K3: combine partials -> w; gumbel-max -> i_t ----------------
__global__ __launch_bounds__(256) void combine_cat_kernel(
    const float* __restrict__ pm, const float* __restrict__ ps,
    const float* __restrict__ pe, int* __restrict__ i_t,
    uint32_t kc0, uint32_t kc1) {
  __shared__ float wv[256];
  __shared__ float wn[256];
  const int tid = threadIdx.x;
  // combine 20 chunks for row=tid
  {
    float M = -INFINITY;
    #pragma unroll 4
    for (int c = 0; c < 20; c++) M = fmaxf(M, pm[tid * 20 + c]);
    float S = 0.f, E = 0.f;
    #pragma unroll 4
    for (int c = 0; c < 20; c++) {
      float sc = expf(pm[tid * 20 + c] - M);
      S += ps[tid * 20 + c] * sc;
      E += pe[tid * 20 + c] * sc;
    }
    wv[tid] = E / S;
  }
  __syncthreads();
  const int b = tid >> 4;
  float mx = -INFINITY;
  for (int j = 0; j < 16; j++) mx = fmaxf(mx, wv[b * 16 + j]);
  float ev = expf(wv[tid] - mx);
  wn[tid] = ev;
  __syncthreads();
  float sum = 0.f;
  for (int j = 0; j < 16; j++) sum += wn[b * 16 + j];
  __syncthreads();
  wn[tid] = ev / sum;
  __syncthreads();
  float best = -INFINITY;
  int bi = 0;
  for (int j = 0; j < 16; j++) {
    uint32_t idx = (uint32_t)tid * 16u + (uint32_t)j;
    float g = jax_gumbel(kc0, kc1, idx);
    float sc = g + wn[b * 16 + j];
    if (sc > best) { best = sc; bi = j; }
  }
  i_t[tid] = bi;
}

// ---------------- K4: head-resample s in [0,256] (302 MB) ----------------
#define HEAD_F4_PER_BP 16448u   // 257 * 64
__global__ __launch_bounds__(256) void head_resample_kernel(
    const float4* __restrict__ Kin, const float4* __restrict__ Vin,
    const float4* __restrict__ Rin,
    const float4* __restrict__ knew, const float4* __restrict__ vnew,
    const float4* __restrict__ rnew,
    const int* __restrict__ i_t,
    float4* __restrict__ Kout, float4* __restrict__ Vout,
    float4* __restrict__ Rout) {
  uint32_t idx = blockIdx.x * 256u + threadIdx.x;   // < 256*16448
  uint32_t bp = idx / HEAD_F4_PER_BP;
  uint32_t rrem = idx - bp * HEAD_F4_PER_BP;
  uint32_t s = rrem >> 6, d4 = rrem & 63u;
  const float4* in; const float4* nw; float4* out;
  if (blockIdx.y == 0)      { in = Kin; nw = knew; out = Kout; }
  else if (blockIdx.y == 1) { in = Vin; nw = vnew; out = Vout; }
  else                      { in = Rin; nw = rnew; out = Rout; }
  uint32_t ip = (uint32_t)i_t[bp];
  uint32_t srcbp = (bp & ~15u) | ip;
  float4 val;
  if (s == T_) val = nw[(srcbp << 6) | d4];
  else         val = in[(srcbp << 15) | (s << 6) | d4];
  out[(bp << 15) | (s << 6) | d4] = val;
}

// ---------------- host ----------------
static void compute_subkeys(uint32_t nk[5][2]) {
  const uint32_t k0 = 0u, k1 = 1234u;
  for (uint32_t j = 0; j < 5; j++)
    threefry2x32_(k0, k1, 0u, j, nk[j][0], nk[j][1]);
}

extern "C" void kernel_launch(void* const* d_in, const int* in_sizes, int n_in,
                              void* d_out, int out_size, void* d_ws, size_t ws_size,
                              hipStream_t stream) {
  const float* x    = (const float*)d_in[0];
  const int*   y    = (const int*)d_in[1];
  const float* Kin  = (const float*)d_in[2];
  const float* Vin  = (const float*)d_in[3];
  const float* Rin  = (const float*)d_in[4];
  const float* wq   = (const float*)d_in[5];  const float* bq = (const float*)d_in[6];
  const float* wk   = (const float*)d_in[7];  const float* bk = (const float*)d_in[8];
  const float* wv   = (const float*)d_in[9];  const float* bv = (const float*)d_in[10];
  const float* wo   = (const float*)d_in[11]; const float* bo = (const float*)d_in[12];
  const float* w1   = (const float*)d_in[13]; const float* b1 = (const float*)d_in[14];
  const float* w2   = (const float*)d_in[15]; const float* b2 = (const float*)d_in[16];
  const float* ln1g = (const float*)d_in[17]; const float* ln1b = (const float*)d_in[18];
  const float* ln2g = (const float*)d_in[19]; const float* ln2b = (const float*)d_in[20];
  const float* w_out = (const float*)d_in[21];
  const float* sigmas = (const float*)d_in[22];
  (void)in_sizes; (void)n_in; (void)out_size; (void)ws_size;

  // output layout (flat f32): r, attn, noise_q, noise_z, K, V, R
  float* out        = (float*)d_out;
  float* r_out      = out;
  float* attn_out   = out + 65536;
  float* noiseq_out = out + 131328;
  float* noisez_out = out + 196864;
  float* K_out      = out + 262400;
  float* V_out      = out + 33816832;
  float* R_out      = out + 67371264;

  // workspace layout (floats)
  float* wsf  = (float*)d_ws;
  float* kws  = wsf;                   // 65536
  float* vws  = wsf + 65536;           // 65536
  float* pm   = wsf + 131072;          // 5120
  float* ps   = wsf + 136192;          // 5120
  float* pe   = wsf + 141312;          // 5120
  int*   i_t  = (int*)(wsf + 146432);  // 256

  uint32_t nk[5][2];
  compute_subkeys(nk);  // 0=q, 1=k, 2=v, 3=z, 4=categorical

  fused_row_kernel<<<ROWS_, 1024, 0, stream>>>(
      x, Kin, Vin, wq, bq, wk, bk, wv, bv, wo, bo, w1, b1, w2, b2,
      ln1g, ln1b, ln2g, ln2b, sigmas,
      kws, vws, attn_out, noiseq_out, noisez_out, r_out,
      nk[0][0], nk[0][1], nk[1][0], nk[1][1], nk[2][0], nk[2][1],
      nk[3][0], nk[3][1]);
  preds_tail_kernel<<<PREDS_BLOCKS + 3 * TAIL_BLOCKS_PER_TENSOR, 256, 0, stream>>>(
      r_out, w_out, y,
      (const float4*)Kin, (const float4*)Vin, (const float4*)Rin,
      (float4*)K_out, (float4*)V_out, (float4*)R_out,
      pm, ps, pe);
  combine_cat_kernel<<<1, 256, 0, stream>>>(pm, ps, pe, i_t,
                                            nk[4][0], nk[4][1]);
  head_resample_kernel<<<dim3(16448, 3), 256, 0, stream>>>(
      (const float4*)Kin, (const float4*)Vin, (const float4*)Rin,
      (const float4*)kws, (const float4*)vws, (const float4*)r_out,
      i_t, (float4*)K_out, (float4*)V_out, (float4*)R_out);
}